// Round 18
// baseline (920.444 us; speedup 1.0000x reference)
//
#include <hip/hip_runtime.h>
#include <math.h>

// FireflyVQ R18: gemm_down retiled 128m x 64n with 64-K LDS buffers
// (two proven [64][32]-swizzled subtiles) -> 96 MFMA per barrier-gap
// (R12-equal) AND grid 1024 (3 blocks/CU, 12 waves/CU; was 512 = 2/CU).
// Per-output FP chains bit-identical to R12/R17 (codes locked).
// Everything else R17-verbatim.

using u16 = unsigned short;
typedef __attribute__((ext_vector_type(8))) short bf16x8;
typedef __attribute__((ext_vector_type(8))) u16 su16x8;
typedef __attribute__((ext_vector_type(4))) float f32x4;

constexpr int NQ = 9, CBS = 1024, CBD = 8;
constexpr int TQ = 2048;
constexpr int NTOK = 16384;
constexpr int APS = 1048576;   // u16 per W_d split plane (512*2048)
#define EPSN 1e-12f

// ---- ws layout (float offsets), ~56.5 MB
constexpr size_t OFF_X2    = 0;                  // [8][512][2048] fp32
constexpr size_t OFF_E0T   = 8388608;            // [16384][72]
constexpr size_t OFF_Q     = 9568256;            // [16384][80] n-major
constexpr size_t OFF_WD    = 10878976;           // W_d [512][2048] fp32
constexpr size_t OFF_WDP   = 11927552;           // 3 u16 planes of W_d
constexpr size_t OFF_WEFF  = 13500416;           // W_eff [2048][512] fp32
constexpr size_t OFF_WX    = 14548992;           // Wx [2048][80]
constexpr size_t OFF_WINN  = 14712832;           // [72][512]
constexpr size_t OFF_WOUTS = 14749696;           // WoutS2 [512][80]
constexpr size_t OFF_CBS   = 14790656;           // [9][2][1024]
constexpr size_t OFF_PT    = 14809088;           // 2340
constexpr size_t OFF_BEFF  = 14811428;           // 72
constexpr size_t OFF_BSUM  = 14811500;           // 512
constexpr size_t OFF_BD    = 14812012;           // 512
constexpr size_t OFF_BUP   = 14812524;           // [512][2]
constexpr size_t OFF_LOSS  = 14813548;           // 1024

// ---------------- prep_small1 (R17 verbatim) ----------------
__global__ void prep_small1(const float* __restrict__ in_v, const float* __restrict__ in_g,
                            const float* __restrict__ out_v, const float* __restrict__ out_g,
                            const float* __restrict__ out_b, const float* __restrict__ codebooks,
                            const float* __restrict__ down_w, const float* __restrict__ down_b,
                            const float* __restrict__ up_w, const float* __restrict__ up_b,
                            float* __restrict__ ws) {
  int bid = blockIdx.x, tid = threadIdx.x;
  int wid4 = tid >> 6, lane = tid & 63;
  if (bid < 18) {
    int wid = bid * 4 + wid4;
    if (wid < 72) {
      const float* v = in_v + (size_t)wid * 512;
      float ss = 0.f;
      for (int c = lane; c < 512; c += 64) ss += v[c] * v[c];
      #pragma unroll
      for (int o = 32; o; o >>= 1) ss += __shfl_xor(ss, o);
      float sc = in_g[wid] / sqrtf(ss);
      float* dst = ws + OFF_WINN + (size_t)wid * 512;
      for (int c = lane; c < 512; c += 64) dst[c] = v[c] * sc;
    }
  } else if (bid < 36) {
    int r = (bid - 18) * 256 + tid;
    if (r < 4608) {
      int i = r >> 9, c = r & 511;
      const float* v = out_v + (size_t)r * 8;
      float ss = 0.f;
      #pragma unroll
      for (int d = 0; d < 8; d++) ss += v[d] * v[d];
      float sc = out_g[r] / sqrtf(ss);
      float* dst = ws + OFF_WOUTS + (size_t)c * 80 + i * 8;
      #pragma unroll
      for (int d = 0; d < 8; d++) dst[d] = v[d] * sc;
    }
  } else if (bid < 72) {
    int r = (bid - 36) * 256 + tid;
    if (r < 9216) {
      int i = r >> 10, j = r & 1023;
      const float* v = codebooks + (size_t)r * 8;
      float ss = 0.f;
      #pragma unroll
      for (int d = 0; d < 8; d++) ss += v[d] * v[d];
      float nm = fmaxf(sqrtf(ss), EPSN);
      float nsq = 0.f;
      #pragma unroll
      for (int d = 0; d < 8; d++) { float cn = v[d] / nm; nsq += cn * cn; }
      ws[OFF_CBS + ((size_t)i * 2 + 0) * 1024 + j] = 2.0f / nm;
      ws[OFF_CBS + ((size_t)i * 2 + 1) * 1024 + j] = nsq;
    }
  } else if (bid < 74) {
    int c = (bid - 72) * 256 + tid;
    if (c < 512) {
      float s = 0.f;
      #pragma unroll
      for (int j = 0; j < 9; j++) s += out_b[j * 512 + c];
      ws[OFF_BSUM + c] = s;
      ws[OFF_WOUTS + (size_t)c * 80 + 72] = s;
      #pragma unroll
      for (int d = 73; d < 80; d++) ws[OFF_WOUTS + (size_t)c * 80 + d] = 0.f;
    }
  } else if (bid < 202) {
    int o = (bid - 74) * 4 + wid4;
    float s = 0.f;
    for (int m = lane; m < 512; m += 64) {
      float w0 = down_w[524288 + (size_t)o * 1024 + m * 2];
      float w1 = down_w[524288 + (size_t)o * 1024 + m * 2 + 1];
      s += (w0 + w1) * down_b[m];
    }
    #pragma unroll
    for (int off = 32; off; off >>= 1) s += __shfl_xor(s, off);
    if (lane == 0) ws[OFF_BD + o] = s + down_b[512 + o];
  } else {
    int gw = (bid - 202) * 256 + tid;
    int c = gw >> 1, j2 = gw & 1;
    float s = 0.f;
    for (int m = 0; m < 512; m++)
      s += up_w[524288 + (size_t)m * 1024 + c * 2 + j2] * up_b[m];
    ws[OFF_BUP + gw] = s + up_b[512 + c];
  }
}

// ---------------- prep2 (R17 verbatim) ----------------
__global__ void prep2(const float* __restrict__ in_b, const float* __restrict__ out_b,
                      float* __restrict__ ws) {
  int gw = blockIdx.x * 4 + (threadIdx.x >> 6), lane = threadIdx.x & 63;
  const float* WinN = ws + OFF_WINN;
  const float* WoutS = ws + OFF_WOUTS;
  if (gw < 2304) {
    int tri = gw >> 6, dd = gw & 63;
    int ip = 1;
    while (tri >= ip * (ip + 1) / 2) ip++;
    int i = tri - ip * (ip - 1) / 2;
    int d = dd >> 3, dp = dd & 7;
    const float* a = WinN + (size_t)(ip * 8 + d) * 512;
    float s = 0.f;
    for (int c = lane; c < 512; c += 64) s += a[c] * WoutS[(size_t)c * 80 + i * 8 + dp];
    #pragma unroll
    for (int o = 32; o; o >>= 1) s += __shfl_xor(s, o);
    if (lane == 0) ws[OFF_PT + (size_t)tri * 65 + dd] = s;
  } else if (gw < 2376) {
    int r = gw - 2304;
    int i = r >> 3;
    const float* a = WinN + (size_t)r * 512;
    float s = 0.f;
    for (int c = lane; c < 512; c += 64) {
      float ob = 0.f;
      for (int j = 0; j < i; j++) ob += out_b[j * 512 + c];
      s += a[c] * ob;
    }
    #pragma unroll
    for (int o = 32; o; o >>= 1) s += __shfl_xor(s, o);
    if (lane == 0) ws[OFF_BEFF + r] = in_b[r] - s;
  }
}

// ---------------- smallmm2 (R17 verbatim) ----------------
__global__ __launch_bounds__(256) void smallmm2(const float* __restrict__ down_w,
                                                const float* __restrict__ up_w,
                                                float* __restrict__ wd,
                                                float* __restrict__ weff) {
  __shared__ float As[32][68];
  __shared__ float Bs[32][68];
  const int tid = threadIdx.x;
  const int tx = tid & 15, ty = tid >> 4;
  const int b0 = blockIdx.x * 64, a0 = blockIdx.y * 64;
  const int which = blockIdx.z >> 2, j = blockIdx.z & 3;
  const int jh = j >> 1, jl = j & 1;
  const float* src = which ? up_w : down_w;
  float acc[4][4];
  #pragma unroll
  for (int i = 0; i < 4; i++)
    #pragma unroll
    for (int k = 0; k < 4; k++) acc[i][k] = 0.f;

  for (int k0 = 0; k0 < 512; k0 += 32) {
    #pragma unroll
    for (int rep = 0; rep < 8; rep++) {
      int f = tid + rep * 256;
      int aa = f >> 5, mm = f & 31;
      size_t ai = which ? (524288 + (size_t)(k0 + mm) * 1024 + (a0 + aa) * 2 + jl)
                        : (524288 + (size_t)(a0 + aa) * 1024 + (k0 + mm) * 2 + jh);
      As[mm][aa] = src[ai];
      int mm2 = f >> 6, bb = f & 63;
      size_t bi = which ? ((size_t)(b0 + bb) * 1024 + (k0 + mm2) * 2 + jh)
                        : ((size_t)(k0 + mm2) * 1024 + (b0 + bb) * 2 + jl);
      Bs[mm2][bb] = src[bi];
    }
    __syncthreads();
    #pragma unroll
    for (int kk = 0; kk < 32; kk++) {
      float av[4], bv[4];
      #pragma unroll
      for (int i = 0; i < 4; i++) av[i] = As[kk][ty * 4 + i];
      #pragma unroll
      for (int i = 0; i < 4; i++) bv[i] = Bs[kk][tx * 4 + i];
      #pragma unroll
      for (int i = 0; i < 4; i++)
        #pragma unroll
        for (int k = 0; k < 4; k++) acc[i][k] = fmaf(av[i], bv[k], acc[i][k]);
    }
    __syncthreads();
  }
  #pragma unroll
  for (int i = 0; i < 4; i++) {
    int a = a0 + ty * 4 + i;
    #pragma unroll
    for (int k = 0; k < 4; k++) {
      int b = b0 + tx * 4 + k;
      if (which) weff[((size_t)a * 4 + j) * 512 + b] = acc[i][k];
      else       wd[(size_t)a * 2048 + b * 4 + j] = acc[i][k];
    }
  }
}

// ---------------- prep_split_wx (R17 verbatim) ----------------
__global__ __launch_bounds__(256) void prep_split_wx(const float* __restrict__ wd,
                                                     u16* __restrict__ wdp,
                                                     const float* __restrict__ weff,
                                                     const float* __restrict__ wouts,
                                                     float* __restrict__ wx) {
  const int tid = threadIdx.x;
  if (blockIdx.x < 4096) {
    int idx = blockIdx.x * 256 + tid;
    float v = wd[idx];
    unsigned u = __float_as_uint(v);
    wdp[idx] = (u16)(u >> 16);
    float r = v - __uint_as_float(u & 0xFFFF0000u);
    unsigned ur = __float_as_uint(r);
    wdp[APS + idx] = (u16)(ur >> 16);
    float r2 = r - __uint_as_float(ur & 0xFFFF0000u);
    wdp[2 * APS + idx] = (u16)(__float_as_uint(r2) >> 16);
    return;
  }
  __shared__ float Wes[16][512];
  __shared__ float WSs[64][80];
  const int m0 = (blockIdx.x - 4096) * 16;
  #pragma unroll
  for (int rep = 0; rep < 32; rep++) {
    int f = tid + rep * 256;
    Wes[f >> 9][f & 511] = weff[(size_t)(m0 + (f >> 9)) * 512 + (f & 511)];
  }
  const int rowq = tid >> 4, rq = tid & 15;
  float accs[5] = {0.f, 0.f, 0.f, 0.f, 0.f};
  for (int k0 = 0; k0 < 512; k0 += 64) {
    __syncthreads();
    #pragma unroll
    for (int rep = 0; rep < 20; rep++) {
      int f = tid + rep * 256;
      int kk = f / 80, col = f % 80;
      WSs[kk][col] = wouts[(size_t)(k0 + kk) * 80 + col];
    }
    __syncthreads();
    #pragma unroll 4
    for (int kk = 0; kk < 64; kk++) {
      float we = Wes[rowq][k0 + kk];
      #pragma unroll
      for (int s = 0; s < 5; s++) accs[s] = fmaf(we, WSs[kk][rq + 16 * s], accs[s]);
    }
  }
  #pragma unroll
  for (int s = 0; s < 5; s++) {
    int r = rq + 16 * s;
    if (r < 73) wx[(size_t)(m0 + rowq) * 80 + r] = accs[s];
  }
  if (tid < 112) {
    int row = tid / 7, col = 73 + tid % 7;
    wx[(size_t)(m0 + row) * 80 + col] = 0.f;
  }
}

// ---------------- gemm_down v5: 128m x 64n, 64-K buffers, grid 1024 ----------------
// 4 waves (2m x 2n, each 64x32). LDS Bp[2][3][2 ksub][64][32] (proven swizzle
// per ksub). 96 MFMA/wave per barrier-gap (= R12). Bit-identical chains.
__global__ __launch_bounds__(256) void gemm_down(const u16* __restrict__ Ap,
                                                 const float* __restrict__ z,
                                                 const float* __restrict__ bias,
                                                 float* __restrict__ Out) {
  constexpr int NS = 3, K = 2048;
  __shared__ u16 Bp[2][NS][2][64][32];
  const int tid = threadIdx.x;
  const int w = tid >> 6, l = tid & 63;
  const int g = l >> 4, li = l & 15;
  const int wr = w >> 1, wc = w & 1;
  const int n0 = blockIdx.x * 64, m0 = blockIdx.y * 128;
  const int nn = tid & 63, kq = tid >> 6;   // row-owner nn, 16-k quarter kq
  const int bb = n0 >> 11;
  const int tb = (n0 & 2047) + nn;

  f32x4 acc[4][2];
  #pragma unroll
  for (int a = 0; a < 4; a++)
    #pragma unroll
    for (int b = 0; b < 2; b++) acc[a][b] = (f32x4){0.f, 0.f, 0.f, 0.f};

  float pvA[16], pvB[16];

#define LOADB(PV, K0)                                                           \
  {                                                                             \
    int c0_ = ((K0) >> 2) + kq * 4;                                             \
    _Pragma("unroll")                                                           \
    for (int cc_ = 0; cc_ < 4; ++cc_)                                           \
      *(float4*)&PV[4 * cc_] =                                                  \
          *(const float4*)(z + ((size_t)(bb * 512 + c0_ + cc_) << 13) + 4 * tb);\
  }

  const int ks = kq >> 1, kw = kq & 1;
  const int sw = (nn >> 1) & 3;
  const int c0 = ((2 * kw) ^ sw) << 3, c1 = ((2 * kw + 1) ^ sw) << 3;

#define STAGE(BUF, PV)                                                          \
  {                                                                             \
    su16x8 pa_[NS], pb_[NS];                                                    \
    _Pragma("unroll")                                                           \
    for (int j_ = 0; j_ < 8; ++j_) {                                            \
      {                                                                         \
        float v_ = PV[j_];                                                      \
        unsigned u_ = __float_as_uint(v_);                                      \
        pa_[0][j_] = (u16)(u_ >> 16);                                           \
        float r_ = v_ - __uint_as_float(u_ & 0xFFFF0000u);                      \
        unsigned ur_ = __float_as_uint(r_);                                     \
        pa_[1][j_] = (u16)(ur_ >> 16);                                          \
        float r2_ = r_ - __uint_as_float(ur_ & 0xFFFF0000u);                    \
        pa_[2][j_] = (u16)(__float_as_uint(r2_) >> 16);                         \
      }                                                                         \
      {                                                                         \
        float v_ = PV[8 + j_];                                                  \
        unsigned u_ = __float_as_uint(v_);                                      \
        pb_[0][j_] = (u16)(u_ >> 16);                                           \
        float r_ = v_ - __uint_as_float(u_ & 0xFFFF0000u);                      \
        unsigned ur_ = __float_as_uint(r_);                                     \
        pb_[1][j_] = (u16)(ur_ >> 16);                                          \
        float r2_ = r_ - __uint_as_float(ur_ & 0xFFFF0000u);                    \
        pb_[2][j_] = (u16)(__float_as_uint(r2_) >> 16);                         \
      }                                                                         \
    }                                                                           \
    _Pragma("unroll")                                                           \
    for (int p_ = 0; p_ < NS; ++p_) {                                           \
      *(su16x8*)&Bp[BUF][p_][ks][nn][c0] = pa_[p_];                             \
      *(su16x8*)&Bp[BUF][p_][ks][nn][c1] = pb_[p_];                             \
    }                                                                           \
  }

#define COMPUTE(BUF, SS, K0)                                                    \
  {                                                                             \
    bf16x8 bfr_[2][NS];                                                         \
    _Pragma("unroll")                                                           \
    for (int fn_ = 0; fn_ < 2; ++fn_) {                                         \
      int row_ = wc * 32 + fn_ * 16 + li;                                       \
      int cs_ = ((g ^ ((row_ >> 1) & 3)) << 3);                                 \
      _Pragma("unroll")                                                         \
      for (int q_ = 0; q_ < NS; ++q_)                                           \
        bfr_[fn_][q_] = *(const bf16x8*)&Bp[BUF][q_][SS][row_][cs_];            \
    }                                                                           \
    const u16* arow_ = Ap + (size_t)(m0 + wr * 64 + li) * K + (K0) + g * 8;     \
    _Pragma("unroll")                                                           \
    for (int fm_ = 0; fm_ < 4; ++fm_) {                                         \
      bf16x8 afr_[NS];                                                          \
      _Pragma("unroll")                                                         \
      for (int p_ = 0; p_ < NS; ++p_)                                           \
        afr_[p_] = *(const bf16x8*)(arow_ + (size_t)p_ * APS + (size_t)fm_ * 16 * K); \
      _Pragma("unroll")                                                         \
      for (int fn_ = 0; fn_ < 2; ++fn_) {                                       \
        f32x4 a_ = acc[fm_][fn_];                                               \
        a_ = __builtin_amdgcn_mfma_f32_16x16x32_bf16(afr_[2], bfr_[fn_][0], a_, 0, 0, 0); \
        a_ = __builtin_amdgcn_mfma_f32_16x16x32_bf16(afr_[1], bfr_[fn_][1], a_, 0, 0, 0); \
        a_ = __builtin_amdgcn_mfma_f32_16x16x32_bf16(afr_[0], bfr_[fn_][2], a_, 0, 0, 0); \
        a_ = __builtin_amdgcn_mfma_f32_16x16x32_bf16(afr_[1], bfr_[fn_][0], a_, 0, 0, 0); \
        a_ = __builtin_amdgcn_mfma_f32_16x16x32_bf16(afr_[0], bfr_[fn_][1], a_, 0, 0, 0); \
        a_ = __builtin_amdgcn_mfma_f32_16x16x32_bf16(afr_[0], bfr_[fn_][0], a_, 0, 0, 0); \
        acc[fm_][fn_] = a_;                                                     \
      }                                                                         \
    }                                                                           \
  }

  LOADB(pvA, 0)
  LOADB(pvB, 64)
  STAGE(0, pvA)
  LOADB(pvA, 128)
  __syncthreads();

  for (int k0 = 0; k0 < K; k0 += 128) {
    STAGE(1, pvB)
    if (k0 + 192 < K) { LOADB(pvB, k0 + 192) }
    COMPUTE(0, 0, k0)
    COMPUTE(0, 1, k0 + 32)
    __syncthreads();
    if (k0 + 128 < K) { STAGE(0, pvA) }
    if (k0 + 256 < K) { LOADB(pvA, k0 + 256) }
    COMPUTE(1, 0, k0 + 64)
    COMPUTE(1, 1, k0 + 96)
    __syncthreads();
  }
#undef LOADB
#undef STAGE
#undef COMPUTE

  const int mb = m0 + wr * 64 + g * 4;
  const int nb = n0 + wc * 32 + li;
  #pragma unroll
  for (int fn = 0; fn < 2; ++fn) {
    int n = nb + fn * 16;
    int b = n >> 11, t = n & 2047;
    #pragma unroll
    for (int fm = 0; fm < 4; ++fm)
      #pragma unroll
      for (int r = 0; r < 4; ++r) {
        int o = mb + fm * 16 + r;
        Out[((size_t)((b << 9) + o)) * 2048 + t] = acc[fm][fn][r] + bias[o];
      }
  }
}

// ---------------- gemm_e0f (R14 verbatim) ----------------
__global__ __launch_bounds__(256) void gemm_e0f(const float* __restrict__ A,
                                                const float* __restrict__ Bsrc,
                                                float* __restrict__ e0t) {
  constexpr int M = 72, K = 512, Tt = 2048;
  __shared__ float As[16][132];
  __shared__ float Bs[16][68];
  int tid = threadIdx.x;
  int tx = tid & 7, ty = tid >> 3;
  int n0 = blockIdx.x * 64;
  int b = n0 / Tt, t0 = n0 % Tt;
  float acc[4][8];
  #pragma unroll
  for (int i = 0; i < 4; i++)
    #pragma unroll
    for (int j = 0; j < 8; j++) acc[i][j] = 0.f;

  for (int k0 = 0; k0 < K; k0 += 16) {
    #pragma unroll
    for (int rep = 0; rep < 2; rep++) {
      int f = tid + rep * 256;
      int row = f >> 2, c4 = (f & 3) << 2;
      int m = row, k = k0 + c4;
      float4 v = make_float4(0.f, 0.f, 0.f, 0.f);
      if (m < M) v = *(const float4*)(A + (size_t)m * K + k);
      As[c4 + 0][row] = v.x; As[c4 + 1][row] = v.y;
      As[c4 + 2][row] = v.z; As[c4 + 3][row] = v.w;
    }
    {
      int kk = tid >> 4, n4 = (tid & 15) << 2;
      float4 v = *(const float4*)(Bsrc + ((size_t)(b * K + k0 + kk)) * Tt + t0 + n4);
      *(float4*)&Bs[kk][n4] = v;
    }
    __syncthreads();
    #pragma unroll
    for (int kk = 0; kk < 16; kk++) {
      float a[4], bb[8];
      #pragma unroll
      for (int i = 0; i < 4; i++) a[i] = As[kk][ty * 4 + i];
      *(float4*)&bb[0] = *(float4*)&Bs[kk][tx * 8];
      *(float4*)&bb[4] = *(float4*)&Bs[kk][tx * 8 + 4];
      #pragma unroll
      for (int i = 0; i < 4; i++)
        #pragma unroll
        for (int j = 0; j < 8; j++) acc[i][j] = fmaf(a[i], bb[j], acc[i][j]);
    }
    __syncthreads();
  }
  #pragma unroll
  for (int j = 0; j < 8; j++) {
    int n = n0 + tx * 8 + j;
    #pragma unroll
    for (int i = 0; i < 4; i++) {
      int m = ty * 4 + i;
      if (m < M) e0t[(size_t)n * M + m] = acc[i][j];
    }
  }
}

// ---------------- xfin (R17 verbatim) ----------------
__global__ __launch_bounds__(256) void xfin(const float* __restrict__ wx,
                                            const float* __restrict__ Q,
                                            const float* __restrict__ bup,
                                            float* __restrict__ xout) {
  __shared__ float Wxs[128][80];
  __shared__ float Qs[128][80];
  const int tid = threadIdx.x;
  const int n0 = blockIdx.x * 128, m0 = blockIdx.y * 128;
  #pragma unroll
  for (int rep = 0; rep < 10; rep++) {
    int f = tid + rep * 256;
    *(float4*)&Wxs[0][f * 4] = *(const float4*)(wx + (size_t)m0 * 80 + f * 4);
    *(float4*)&Qs[0][f * 4] = *(const float4*)(Q + (size_t)n0 * 80 + f * 4);
  }
  __syncthreads();

  const int txn = tid & 15, tym = tid >> 4;
  float acc[8][8];
  #pragma unroll
  for (int i = 0; i < 8; i++)
    #pragma unroll
    for (int j = 0; j < 8; j++) acc[i][j] = 0.f;

  #pragma unroll 2
  for (int r4 = 0; r4 < 18; r4++) {
    float4 wv[8], qv[8];
    #pragma unroll
    for (int i = 0; i < 8; i++) wv[i] = *(const float4*)&Wxs[tym * 8 + i][r4 * 4];
    #pragma unroll
    for (int j = 0; j < 8; j++) qv[j] = *(const float4*)&Qs[txn * 8 + j][r4 * 4];
    #pragma unroll
    for (int i = 0; i < 8; i++)
      #pragma unroll
      for (int j = 0; j < 8; j++) {
        acc[i][j] = fmaf(wv[i].x, qv[j].x, acc[i][j]);
        acc[i][j] = fmaf(wv[i].y, qv[j].y, acc[i][j]);
        acc[i][j] = fmaf(wv[i].z, qv[j].z, acc[i][j]);
        acc[i][j] = fmaf(wv[i].w, qv[j].w, acc[i][j]);
      }
  }

  float bxv[8];
  #pragma unroll
  for (int mi = 0; mi < 8; mi++) {
    int mp = m0 + tym * 8 + mi;
    bxv[mi] = Wxs[tym * 8 + mi][72] + bup[(mp >> 2) * 2 + (mp & 1)];
  }
  #pragma unroll
  for (int cg = 0; cg < 2; cg++) {
    int mp0 = m0 + tym * 8 + cg * 4;
    int c = mp0 >> 2;
    #pragma unroll
    for (int j = 0; j < 8; j++) {
      int n = n0 + txn * 8 + j;
      int b = n >> 11, t = n & 2047;
      float4 sv = make_float4(acc[cg * 4 + 0][j] + bxv[cg * 4 + 0],
                              acc[cg * 4 + 1][j] + bxv[cg * 4 + 1],
                              acc[cg * 4 + 2][j] + bxv[cg * 4 + 2],
                              acc[cg * 4 + 3][j] + bxv[cg * 4 + 3]);
      *(float4*)&xout[((size_t)((b << 9) + c)) * 8192 + 4 * t] = sv;
    }
  }
}

// ---------------- RVQ core (R17 verbatim) ----------------
__global__ __launch_bounds__(256) void rvq_kernel(const float* __restrict__ codebooks,
                                                  const float* __restrict__ e0t,
                                                  const float* __restrict__ cbsW,
                                                  const float* __restrict__ ptW,
                                                  const float* __restrict__ beffW,
                                                  float* __restrict__ Qout,
                                                  float* __restrict__ codesOut,
                                                  float* __restrict__ lossPart) {
  __shared__ float cbv[8][1024];
  __shared__ float cbs2[2][1024];
  __shared__ float est[16][72];
  __shared__ float lred[4];
  int tid = threadIdx.x, wid = tid >> 6, lane = tid & 63;
  int nb0 = blockIdx.x * 16;
  for (int idx = tid; idx < 16 * 72; idx += 256)
    est[idx / 72][idx % 72] = e0t[(size_t)nb0 * 72 + idx] + beffW[idx % 72];
  float lossLocal = 0.f;

  for (int i = 0; i < NQ; i++) {
    __syncthreads();
    const float* cbg = codebooks + (size_t)i * CBS * CBD;
    for (int lin = tid; lin < 2048; lin += 256) {
      int j = lin >> 1, half = (lin & 1) << 2;
      float4 v = *(const float4*)(cbg + (size_t)j * 8 + half);
      cbv[half + 0][j] = v.x; cbv[half + 1][j] = v.y;
      cbv[half + 2][j] = v.z; cbv[half + 3][j] = v.w;
    }
    for (int lin = tid; lin < 1024; lin += 256) {
      cbs2[0][lin] = cbsW[((size_t)i * 2 + 0) * 1024 + lin];
      cbs2[1][lin] = cbsW[((size_t)i * 2 + 1) * 1024 + lin];
    }
    __syncthreads();

    float ze[4][8], en[4][8];
    #pragma unroll
    for (int w = 0; w < 4; w++) {
      int tokl = wid * 4 + w;
      float ss = 0.f;
      #pragma unroll
      for (int d = 0; d < 8; d++) { float v = est[tokl][i * 8 + d]; ze[w][d] = v; ss += v * v; }
      float inv = 1.0f / fmaxf(sqrtf(ss), EPSN);
      #pragma unroll
      for (int d = 0; d < 8; d++) en[w][d] = ze[w][d] * inv;
    }
    float best[4]; int bidx[4];
    #pragma unroll
    for (int w = 0; w < 4; w++) { best[w] = -INFINITY; bidx[w] = 0; }
    #pragma unroll 4
    for (int r = 0; r < 16; r++) {
      int j = lane + (r << 6);
      float c0 = cbv[0][j], c1 = cbv[1][j], c2 = cbv[2][j], c3 = cbv[3][j];
      float c4 = cbv[4][j], c5 = cbv[5][j], c6 = cbv[6][j], c7 = cbv[7][j];
      float ti = cbs2[0][j], ns = cbs2[1][j];
      #pragma unroll
      for (int w = 0; w < 4; w++) {
        float dt = en[w][0] * c0;
        dt = fmaf(en[w][1], c1, dt); dt = fmaf(en[w][2], c2, dt);
        dt = fmaf(en[w][3], c3, dt); dt = fmaf(en[w][4], c4, dt);
        dt = fmaf(en[w][5], c5, dt); dt = fmaf(en[w][6], c6, dt);
        dt = fmaf(en[w][7], c7, dt);
        float s = fmaf(dt, ti, -ns);
        if (s > best[w]) { best[w] = s; bidx[w] = j; }
      }
    }
    #pragma unroll
    for (int w = 0; w < 4; w++) {
      #pragma unroll
      for (int off = 32; off; off >>= 1) {
        float so = __shfl_xor(best[w], off);
        int jo = __shfl_xor(bidx[w], off);
        if (so > best[w] || (so == best[w] && jo < bidx[w])) { best[w] = so; bidx[w] = jo; }
      }
    }
    int d = lane & 7;
    #pragma unroll
    for (int w = 0; w < 4; w++) {
      int jstar = bidx[w];
      int tokl = wid * 4 + w;
      int n = nb0 + tokl;
      float qd = cbv[d][jstar];
      float diff = ze[w][d] - qd;
      float sq = diff * diff;
      sq += __shfl_xor(sq, 1); sq += __shfl_xor(sq, 2); sq += __shfl_xor(sq, 4);
      if (lane == 0) lossLocal += sq;
      if (lane < 8) Qout[(size_t)n * 80 + i * 8 + lane] = qd;
      if (lane == 0) codesOut[(size_t)((n >> 11) * NQ + i) * TQ + (n & (TQ - 1))] = (float)jstar;
      if (i < NQ - 1) {
        int f = lane >> 3, d2 = lane & 7;
        int ip = i + 1 + f;
        if (ip < NQ) {
          int tri = (ip * (ip - 1)) / 2 + i;
          const float* prow = ptW + (size_t)tri * 65 + d2 * 8;
          float s = 0.f;
          #pragma unroll
          for (int dp = 0; dp < 8; dp++) s = fmaf(prow[dp], cbv[dp][jstar], s);
          est[tokl][ip * 8 + d2] -= s;
        }
      }
    }
  }
  if (lane == 0) lred[wid] = lossLocal;
  __syncthreads();
  if (tid == 0) {
    float s = ((lred[0] + lred[1]) + lred[2]) + lred[3];
    lossPart[blockIdx.x] = s;
  }
}

__global__ void loss_fin(const float* __restrict__ lossPart, float* __restrict__ out) {
  __shared__ float s[256];
  int tid = threadIdx.x;
  float v = 0.f;
  for (int r = 0; r < 4; r++) v += lossPart[tid + r * 256];
  s[tid] = v;
  __syncthreads();
  for (int w = 128; w; w >>= 1) {
    if (tid < w) s[tid] += s[tid + w];
    __syncthreads();
  }
  if (tid == 0) {
    float total = s[0] / 131072.0f;
    out[0] = total;
    out[1] = total;
  }
}

// ---------------- launch ----------------
extern "C" void kernel_launch(void* const* d_in, const int* in_sizes, int n_in,
                              void* d_out, int out_size, void* d_ws, size_t ws_size,
                              hipStream_t stream) {
  const float* z      = (const float*)d_in[0];
  const float* down_w = (const float*)d_in[1];
  const float* down_b = (const float*)d_in[2];
  const float* up_w   = (const float*)d_in[3];
  const float* up_b   = (const float*)d_in[4];
  const float* in_v   = (const float*)d_in[5];
  const float* in_g   = (const float*)d_in[6];
  const float* in_b   = (const float*)d_in[7];
  const float* out_v  = (const float*)d_in[8];
  const float* out_g  = (const float*)d_in[9];
  const float* out_b  = (const float*)d_in[10];
  const float* codebooks = (const float*)d_in[11];
  float* ws = (float*)d_ws;
  float* xout = (float*)d_out;
  float* codesOut = xout + (size_t)8 * 512 * 8192;
  float* lossOut = codesOut + (size_t)8 * NQ * TQ;

  hipLaunchKernelGGL(prep_small1, dim3(206), dim3(256), 0, stream,
                     in_v, in_g, out_v, out_g, out_b, codebooks,
                     down_w, down_b, up_w, up_b, ws);
  hipLaunchKernelGGL(prep2, dim3(594), dim3(256), 0, stream, in_b, out_b, ws);
  hipLaunchKernelGGL(smallmm2, dim3(8, 8, 8), dim3(256), 0, stream,
                     down_w, up_w, ws + OFF_WD, ws + OFF_WEFF);
  hipLaunchKernelGGL(prep_split_wx, dim3(4224), dim3(256), 0, stream,
                     ws + OFF_WD, (u16*)(ws + OFF_WDP),
                     ws + OFF_WEFF, ws + OFF_WOUTS, ws + OFF_WX);
  // fused down: x2 = W_d(3-split) @ zg + b_d  (retiled, grid 1024, bit-exact)
  hipLaunchKernelGGL(gemm_down, dim3(256, 4), dim3(256), 0, stream,
                     (const u16*)(ws + OFF_WDP), z, ws + OFF_BD, ws + OFF_X2);
  // e0t = WinN @ x2
  hipLaunchKernelGGL(gemm_e0f, dim3(256), dim3(256), 0, stream,
                     ws + OFF_WINN, ws + OFF_X2, ws + OFF_E0T);
  // RVQ
  hipLaunchKernelGGL(rvq_kernel, dim3(1024), dim3(256), 0, stream,
                     codebooks, ws + OFF_E0T, ws + OFF_CBS, ws + OFF_PT, ws + OFF_BEFF,
                     ws + OFF_Q, codesOut, ws + OFF_LOSS);
  // x = Wx @ Q + bx
  hipLaunchKernelGGL(xfin, dim3(128, 16), dim3(256), 0, stream,
                     ws + OFF_WX, ws + OFF_Q, ws + OFF_BUP, xout);
  hipLaunchKernelGGL(loss_fin, dim3(1), dim3(256), 0, stream, ws + OFF_LOSS, lossOut);
}

// Round 19
// 914.986 us; speedup vs baseline: 1.0060x; 1.0060x over previous
//
#include <hip/hip_runtime.h>
#include <math.h>

// FireflyVQ R19: gemm_down = R17-verbatim (277us local optimum; R18 retile
// reverted). Rest-fusion, all bit-exact-safe:
//  - e0 folded INTO rvq (serial-k fmaf chain reproduced exactly; e0f kernel
//    and e0t buffer eliminated)
//  - launches 9 -> 5: prep_small1+smallmm2, prep2+prep_split_wx, xfin+loss.

using u16 = unsigned short;
typedef __attribute__((ext_vector_type(8))) short bf16x8;
typedef __attribute__((ext_vector_type(8))) u16 su16x8;
typedef __attribute__((ext_vector_type(4))) float f32x4;

constexpr int NQ = 9, CBS = 1024, CBD = 8;
constexpr int TQ = 2048;
constexpr int NTOK = 16384;
constexpr int APS = 1048576;   // u16 per W_d split plane (512*2048)
#define EPSN 1e-12f

// ---- ws layout (float offsets)
constexpr size_t OFF_X2    = 0;                  // [8][512][2048] fp32
constexpr size_t OFF_Q     = 9568256;            // [16384][80] n-major
constexpr size_t OFF_WD    = 10878976;           // W_d [512][2048] fp32
constexpr size_t OFF_WDP   = 11927552;           // 3 u16 planes of W_d
constexpr size_t OFF_WEFF  = 13500416;           // W_eff [2048][512] fp32
constexpr size_t OFF_WX    = 14548992;           // Wx [2048][80]
constexpr size_t OFF_WINN  = 14712832;           // [72][512]
constexpr size_t OFF_WOUTS = 14749696;           // WoutS2 [512][80]
constexpr size_t OFF_CBS   = 14790656;           // [9][2][1024]
constexpr size_t OFF_PT    = 14809088;           // 2340
constexpr size_t OFF_BEFF  = 14811428;           // 72
constexpr size_t OFF_BSUM  = 14811500;           // 512
constexpr size_t OFF_BD    = 14812012;           // 512
constexpr size_t OFF_BUP   = 14812524;           // [512][2]
constexpr size_t OFF_LOSS  = 14813548;           // 1024

// ---------------- K1: prep_small1 (blocks 0..205) + smallmm2 (206..717) ----------------
__global__ __launch_bounds__(256) void prep_all1(const float* __restrict__ in_v,
                                                 const float* __restrict__ in_g,
                                                 const float* __restrict__ out_v,
                                                 const float* __restrict__ out_g,
                                                 const float* __restrict__ out_b,
                                                 const float* __restrict__ codebooks,
                                                 const float* __restrict__ down_w,
                                                 const float* __restrict__ down_b,
                                                 const float* __restrict__ up_w,
                                                 const float* __restrict__ up_b,
                                                 float* __restrict__ ws) {
  int bid = blockIdx.x, tid = threadIdx.x;
  if (bid < 206) {
    int wid4 = tid >> 6, lane = tid & 63;
    if (bid < 18) {  // WinN rows (locked)
      int wid = bid * 4 + wid4;
      if (wid < 72) {
        const float* v = in_v + (size_t)wid * 512;
        float ss = 0.f;
        for (int c = lane; c < 512; c += 64) ss += v[c] * v[c];
        #pragma unroll
        for (int o = 32; o; o >>= 1) ss += __shfl_xor(ss, o);
        float sc = in_g[wid] / sqrtf(ss);
        float* dst = ws + OFF_WINN + (size_t)wid * 512;
        for (int c = lane; c < 512; c += 64) dst[c] = v[c] * sc;
      }
    } else if (bid < 36) {  // WoutS2 cols 0..71 (locked)
      int r = (bid - 18) * 256 + tid;
      if (r < 4608) {
        int i = r >> 9, c = r & 511;
        const float* v = out_v + (size_t)r * 8;
        float ss = 0.f;
        #pragma unroll
        for (int d = 0; d < 8; d++) ss += v[d] * v[d];
        float sc = out_g[r] / sqrtf(ss);
        float* dst = ws + OFF_WOUTS + (size_t)c * 80 + i * 8;
        #pragma unroll
        for (int d = 0; d < 8; d++) dst[d] = v[d] * sc;
      }
    } else if (bid < 72) {  // codebook scalars (locked)
      int r = (bid - 36) * 256 + tid;
      if (r < 9216) {
        int i = r >> 10, j = r & 1023;
        const float* v = codebooks + (size_t)r * 8;
        float ss = 0.f;
        #pragma unroll
        for (int d = 0; d < 8; d++) ss += v[d] * v[d];
        float nm = fmaxf(sqrtf(ss), EPSN);
        float nsq = 0.f;
        #pragma unroll
        for (int d = 0; d < 8; d++) { float cn = v[d] / nm; nsq += cn * cn; }
        ws[OFF_CBS + ((size_t)i * 2 + 0) * 1024 + j] = 2.0f / nm;
        ws[OFF_CBS + ((size_t)i * 2 + 1) * 1024 + j] = nsq;
      }
    } else if (bid < 74) {  // bsum + WoutS2 col 72..79 (locked)
      int c = (bid - 72) * 256 + tid;
      if (c < 512) {
        float s = 0.f;
        #pragma unroll
        for (int j = 0; j < 9; j++) s += out_b[j * 512 + c];
        ws[OFF_BSUM + c] = s;
        ws[OFF_WOUTS + (size_t)c * 80 + 72] = s;
        #pragma unroll
        for (int d = 73; d < 80; d++) ws[OFF_WOUTS + (size_t)c * 80 + d] = 0.f;
      }
    } else if (bid < 202) {  // b_d[o] (locked)
      int o = (bid - 74) * 4 + wid4;
      float s = 0.f;
      for (int m = lane; m < 512; m += 64) {
        float w0 = down_w[524288 + (size_t)o * 1024 + m * 2];
        float w1 = down_w[524288 + (size_t)o * 1024 + m * 2 + 1];
        s += (w0 + w1) * down_b[m];
      }
      #pragma unroll
      for (int off = 32; off; off >>= 1) s += __shfl_xor(s, off);
      if (lane == 0) ws[OFF_BD + o] = s + down_b[512 + o];
    } else {  // bup (x-only)
      int gw = (bid - 202) * 256 + tid;
      int c = gw >> 1, j2 = gw & 1;
      float s = 0.f;
      for (int m = 0; m < 512; m++)
        s += up_w[524288 + (size_t)m * 1024 + c * 2 + j2] * up_b[m];
      ws[OFF_BUP + gw] = s + up_b[512 + c];
    }
    return;
  }
  // ---- smallmm2 part
  __shared__ float As[32][68];
  __shared__ float Bs[32][68];
  const int bid2 = bid - 206;
  const int tx = tid & 15, ty = tid >> 4;
  const int b0 = (bid2 & 7) * 64, a0 = ((bid2 >> 3) & 7) * 64;
  const int zz = bid2 >> 6;
  const int which = zz >> 2, j = zz & 3;
  const int jh = j >> 1, jl = j & 1;
  const float* src = which ? up_w : down_w;
  float acc[4][4];
  #pragma unroll
  for (int i = 0; i < 4; i++)
    #pragma unroll
    for (int k = 0; k < 4; k++) acc[i][k] = 0.f;

  for (int k0 = 0; k0 < 512; k0 += 32) {
    #pragma unroll
    for (int rep = 0; rep < 8; rep++) {
      int f = tid + rep * 256;
      int aa = f >> 5, mm = f & 31;
      size_t ai = which ? (524288 + (size_t)(k0 + mm) * 1024 + (a0 + aa) * 2 + jl)
                        : (524288 + (size_t)(a0 + aa) * 1024 + (k0 + mm) * 2 + jh);
      As[mm][aa] = src[ai];
      int mm2 = f >> 6, bb = f & 63;
      size_t bi = which ? ((size_t)(b0 + bb) * 1024 + (k0 + mm2) * 2 + jh)
                        : ((size_t)(k0 + mm2) * 1024 + (b0 + bb) * 2 + jl);
      Bs[mm2][bb] = src[bi];
    }
    __syncthreads();
    #pragma unroll
    for (int kk = 0; kk < 32; kk++) {
      float av[4], bv[4];
      #pragma unroll
      for (int i = 0; i < 4; i++) av[i] = As[kk][ty * 4 + i];
      #pragma unroll
      for (int i = 0; i < 4; i++) bv[i] = Bs[kk][tx * 4 + i];
      #pragma unroll
      for (int i = 0; i < 4; i++)
        #pragma unroll
        for (int k = 0; k < 4; k++) acc[i][k] = fmaf(av[i], bv[k], acc[i][k]);
    }
    __syncthreads();
  }
  float* wd = ws + OFF_WD;
  float* weff = ws + OFF_WEFF;
  #pragma unroll
  for (int i = 0; i < 4; i++) {
    int a = a0 + ty * 4 + i;
    #pragma unroll
    for (int k = 0; k < 4; k++) {
      int b = b0 + tx * 4 + k;
      if (which) weff[((size_t)a * 4 + j) * 512 + b] = acc[i][k];
      else       wd[(size_t)a * 2048 + b * 4 + j] = acc[i][k];
    }
  }
}

// ---------------- K2: prep2 (blocks 0..593) + prep_split_wx (594..4817) ----------------
__global__ __launch_bounds__(256) void prep_all2(const float* __restrict__ in_b,
                                                 const float* __restrict__ out_b,
                                                 float* __restrict__ ws) {
  const int tid = threadIdx.x;
  if (blockIdx.x < 594) {  // prep2 (locked)
    int gw = blockIdx.x * 4 + (tid >> 6), lane = tid & 63;
    const float* WinN = ws + OFF_WINN;
    const float* WoutS = ws + OFF_WOUTS;
    if (gw < 2304) {
      int tri = gw >> 6, dd = gw & 63;
      int ip = 1;
      while (tri >= ip * (ip + 1) / 2) ip++;
      int i = tri - ip * (ip - 1) / 2;
      int d = dd >> 3, dp = dd & 7;
      const float* a = WinN + (size_t)(ip * 8 + d) * 512;
      float s = 0.f;
      for (int c = lane; c < 512; c += 64) s += a[c] * WoutS[(size_t)c * 80 + i * 8 + dp];
      #pragma unroll
      for (int o = 32; o; o >>= 1) s += __shfl_xor(s, o);
      if (lane == 0) ws[OFF_PT + (size_t)tri * 65 + dd] = s;
    } else if (gw < 2376) {
      int r = gw - 2304;
      int i = r >> 3;
      const float* a = WinN + (size_t)r * 512;
      float s = 0.f;
      for (int c = lane; c < 512; c += 64) {
        float ob = 0.f;
        for (int j = 0; j < i; j++) ob += out_b[j * 512 + c];
        s += a[c] * ob;
      }
      #pragma unroll
      for (int o = 32; o; o >>= 1) s += __shfl_xor(s, o);
      if (lane == 0) ws[OFF_BEFF + r] = in_b[r] - s;
    }
    return;
  }
  const int bid2 = blockIdx.x - 594;
  if (bid2 < 4096) {  // wdsplit
    int idx = bid2 * 256 + tid;
    const float* wd = ws + OFF_WD;
    u16* wdp = (u16*)(ws + OFF_WDP);
    float v = wd[idx];
    unsigned u = __float_as_uint(v);
    wdp[idx] = (u16)(u >> 16);
    float r = v - __uint_as_float(u & 0xFFFF0000u);
    unsigned ur = __float_as_uint(r);
    wdp[APS + idx] = (u16)(ur >> 16);
    float r2 = r - __uint_as_float(ur & 0xFFFF0000u);
    wdp[2 * APS + idx] = (u16)(__float_as_uint(r2) >> 16);
    return;
  }
  // prep_wx
  __shared__ float Wes[16][512];
  __shared__ float WSs[64][80];
  const float* weff = ws + OFF_WEFF;
  const float* wouts = ws + OFF_WOUTS;
  float* wx = ws + OFF_WX;
  const int m0 = (bid2 - 4096) * 16;
  #pragma unroll
  for (int rep = 0; rep < 32; rep++) {
    int f = tid + rep * 256;
    Wes[f >> 9][f & 511] = weff[(size_t)(m0 + (f >> 9)) * 512 + (f & 511)];
  }
  const int rowq = tid >> 4, rq = tid & 15;
  float accs[5] = {0.f, 0.f, 0.f, 0.f, 0.f};
  for (int k0 = 0; k0 < 512; k0 += 64) {
    __syncthreads();
    #pragma unroll
    for (int rep = 0; rep < 20; rep++) {
      int f = tid + rep * 256;
      int kk = f / 80, col = f % 80;
      WSs[kk][col] = wouts[(size_t)(k0 + kk) * 80 + col];
    }
    __syncthreads();
    #pragma unroll 4
    for (int kk = 0; kk < 64; kk++) {
      float we = Wes[rowq][k0 + kk];
      #pragma unroll
      for (int s = 0; s < 5; s++) accs[s] = fmaf(we, WSs[kk][rq + 16 * s], accs[s]);
    }
  }
  #pragma unroll
  for (int s = 0; s < 5; s++) {
    int r = rq + 16 * s;
    if (r < 73) wx[(size_t)(m0 + rowq) * 80 + r] = accs[s];
  }
  if (tid < 112) {
    int row = tid / 7, col = 73 + tid % 7;
    wx[(size_t)(m0 + row) * 80 + col] = 0.f;
  }
}

// ---------------- gemm_down (R17 verbatim: 128x128, 4 waves, 277us) ----------------
__global__ __launch_bounds__(256) void gemm_down(const u16* __restrict__ Ap,
                                                 const float* __restrict__ z,
                                                 const float* __restrict__ bias,
                                                 float* __restrict__ Out) {
  constexpr int NS = 3, K = 2048;
  __shared__ u16 Bp[2][NS][128][32];
  const int tid = threadIdx.x;
  const int w = tid >> 6, l = tid & 63;
  const int g = l >> 4, li = l & 15;
  const int wr = w >> 1, wc = w & 1;
  const int n0 = blockIdx.x * 128, m0 = blockIdx.y * 128;
  const int nn = tid & 127, kw = tid >> 7;
  const int bb = n0 >> 11;
  const int tb = (n0 & 2047) + nn;

  f32x4 acc[4][4];
  #pragma unroll
  for (int a = 0; a < 4; a++)
    #pragma unroll
    for (int b = 0; b < 4; b++) acc[a][b] = (f32x4){0.f, 0.f, 0.f, 0.f};

  float pvA[16], pvB[16];

#define LOADB(PV, K0)                                                           \
  {                                                                             \
    int c0_ = ((K0) >> 2) + kw * 4;                                             \
    _Pragma("unroll")                                                           \
    for (int cc_ = 0; cc_ < 4; ++cc_)                                           \
      *(float4*)&PV[4 * cc_] =                                                  \
          *(const float4*)(z + ((size_t)(bb * 512 + c0_ + cc_) << 13) + 4 * tb);\
  }

  const int sw = (nn >> 1) & 3;
  const int c0 = ((2 * kw) ^ sw) << 3, c1 = ((2 * kw + 1) ^ sw) << 3;

#define STAGE(BUF, PV)                                                          \
  {                                                                             \
    su16x8 pa_[NS], pb_[NS];                                                    \
    _Pragma("unroll")                                                           \
    for (int j_ = 0; j_ < 8; ++j_) {                                            \
      {                                                                         \
        float v_ = PV[j_];                                                      \
        unsigned u_ = __float_as_uint(v_);                                      \
        pa_[0][j_] = (u16)(u_ >> 16);                                           \
        float r_ = v_ - __uint_as_float(u_ & 0xFFFF0000u);                      \
        unsigned ur_ = __float_as_uint(r_);                                     \
        pa_[1][j_] = (u16)(ur_ >> 16);                                          \
        float r2_ = r_ - __uint_as_float(ur_ & 0xFFFF0000u);                    \
        pa_[2][j_] = (u16)(__float_as_uint(r2_) >> 16);                         \
      }                                                                         \
      {                                                                         \
        float v_ = PV[8 + j_];                                                  \
        unsigned u_ = __float_as_uint(v_);                                      \
        pb_[0][j_] = (u16)(u_ >> 16);                                           \
        float r_ = v_ - __uint_as_float(u_ & 0xFFFF0000u);                      \
        unsigned ur_ = __float_as_uint(r_);                                     \
        pb_[1][j_] = (u16)(ur_ >> 16);                                          \
        float r2_ = r_ - __uint_as_float(ur_ & 0xFFFF0000u);                    \
        pb_[2][j_] = (u16)(__float_as_uint(r2_) >> 16);                         \
      }                                                                         \
    }                                                                           \
    _Pragma("unroll")                                                           \
    for (int p_ = 0; p_ < NS; ++p_) {                                           \
      *(su16x8*)&Bp[BUF][p_][nn][c0] = pa_[p_];                                 \
      *(su16x8*)&Bp[BUF][p_][nn][c1] = pb_[p_];                                 \
    }                                                                           \
  }

#define COMPUTE(BUF, K0)                                                        \
  {                                                                             \
    bf16x8 bfr_[4][NS];                                                         \
    _Pragma("unroll")                                                           \
    for (int fn_ = 0; fn_ < 4; ++fn_) {                                         \
      int row_ = wc * 64 + fn_ * 16 + li;                                       \
      int cs_ = ((g ^ ((row_ >> 1) & 3)) << 3);                                 \
      _Pragma("unroll")                                                         \
      for (int q_ = 0; q_ < NS; ++q_)                                           \
        bfr_[fn_][q_] = *(const bf16x8*)&Bp[BUF][q_][row_][cs_];                \
    }                                                                           \
    const u16* arow_ = Ap + (size_t)(m0 + wr * 64 + li) * K + (K0) + g * 8;     \
    _Pragma("unroll")                                                           \
    for (int fm_ = 0; fm_ < 4; ++fm_) {                                         \
      bf16x8 afr_[NS];                                                          \
      _Pragma("unroll")                                                         \
      for (int p_ = 0; p_ < NS; ++p_)                                           \
        afr_[p_] = *(const bf16x8*)(arow_ + (size_t)p_ * APS + (size_t)fm_ * 16 * K); \
      _Pragma("unroll")                                                         \
      for (int fn_ = 0; fn_ < 4; ++fn_) {                                       \
        f32x4 a_ = acc[fm_][fn_];                                               \
        a_ = __builtin_amdgcn_mfma_f32_16x16x32_bf16(afr_[2], bfr_[fn_][0], a_, 0, 0, 0); \
        a_ = __builtin_amdgcn_mfma_f32_16x16x32_bf16(afr_[1], bfr_[fn_][1], a_, 0, 0, 0); \
        a_ = __builtin_amdgcn_mfma_f32_16x16x32_bf16(afr_[0], bfr_[fn_][2], a_, 0, 0, 0); \
        a_ = __builtin_amdgcn_mfma_f32_16x16x32_bf16(afr_[1], bfr_[fn_][0], a_, 0, 0, 0); \
        a_ = __builtin_amdgcn_mfma_f32_16x16x32_bf16(afr_[0], bfr_[fn_][1], a_, 0, 0, 0); \
        a_ = __builtin_amdgcn_mfma_f32_16x16x32_bf16(afr_[0], bfr_[fn_][0], a_, 0, 0, 0); \
        acc[fm_][fn_] = a_;                                                     \
      }                                                                         \
    }                                                                           \
  }

  LOADB(pvA, 0)
  LOADB(pvB, 32)
  STAGE(0, pvA)
  LOADB(pvA, 64)
  __syncthreads();

  for (int k0 = 0; k0 < K; k0 += 64) {
    STAGE(1, pvB)
    if (k0 + 96 < K) { LOADB(pvB, k0 + 96) }
    COMPUTE(0, k0)
    __syncthreads();
    if (k0 + 64 < K) { STAGE(0, pvA) }
    if (k0 + 128 < K) { LOADB(pvA, k0 + 128) }
    COMPUTE(1, k0 + 32)
    __syncthreads();
  }
#undef LOADB
#undef STAGE
#undef COMPUTE

  const int mb = m0 + wr * 64 + g * 4;
  const int nb = n0 + wc * 64 + li;
  #pragma unroll
  for (int fn = 0; fn < 4; ++fn) {
    int n = nb + fn * 16;
    int b = n >> 11, t = n & 2047;
    #pragma unroll
    for (int fm = 0; fm < 4; ++fm)
      #pragma unroll
      for (int r = 0; r < 4; ++r) {
        int o = mb + fm * 16 + r;
        Out[((size_t)((b << 9) + o)) * 2048 + t] = acc[fm][fn][r] + bias[o];
      }
  }
}

// ---------------- RVQ core with in-block e0 (bit-exact fold of gemm_e0f) ----------------
__global__ __launch_bounds__(256) void rvq_kernel(const float* __restrict__ codebooks,
                                                  const float* __restrict__ x2,
                                                  const float* __restrict__ winn,
                                                  const float* __restrict__ cbsW,
                                                  const float* __restrict__ ptW,
                                                  const float* __restrict__ beffW,
                                                  float* __restrict__ Qout,
                                                  float* __restrict__ codesOut,
                                                  float* __restrict__ lossPart) {
  __shared__ float cbv[8][1024];
  __shared__ float cbs2[2][1024];
  __shared__ float est[16][72];
  __shared__ float lred[4];
  int tid = threadIdx.x, wid = tid >> 6, lane = tid & 63;
  int nb0 = blockIdx.x * 16;

  // in-block e0: est[tokl][m] = (serial-k ascending fmaf chain, = gemm_e0f) + beff[m]
  for (int idx = tid; idx < 1152; idx += 256) {
    int m = idx >> 4, tokl = idx & 15;
    int n = nb0 + tokl;
    int b = n >> 11, t = n & 2047;
    const float* xcol = x2 + ((size_t)b * 512) * 2048 + t;
    const float* wrow = winn + (size_t)m * 512;
    float acc = 0.f;
    for (int k = 0; k < 512; ++k)
      acc = fmaf(wrow[k], xcol[(size_t)k * 2048], acc);
    est[tokl][m] = acc + beffW[m];
  }
  float lossLocal = 0.f;

  for (int i = 0; i < NQ; i++) {
    __syncthreads();
    const float* cbg = codebooks + (size_t)i * CBS * CBD;
    for (int lin = tid; lin < 2048; lin += 256) {
      int j = lin >> 1, half = (lin & 1) << 2;
      float4 v = *(const float4*)(cbg + (size_t)j * 8 + half);
      cbv[half + 0][j] = v.x; cbv[half + 1][j] = v.y;
      cbv[half + 2][j] = v.z; cbv[half + 3][j] = v.w;
    }
    for (int lin = tid; lin < 1024; lin += 256) {
      cbs2[0][lin] = cbsW[((size_t)i * 2 + 0) * 1024 + lin];
      cbs2[1][lin] = cbsW[((size_t)i * 2 + 1) * 1024 + lin];
    }
    __syncthreads();

    float ze[4][8], en[4][8];
    #pragma unroll
    for (int w = 0; w < 4; w++) {
      int tokl = wid * 4 + w;
      float ss = 0.f;
      #pragma unroll
      for (int d = 0; d < 8; d++) { float v = est[tokl][i * 8 + d]; ze[w][d] = v; ss += v * v; }
      float inv = 1.0f / fmaxf(sqrtf(ss), EPSN);
      #pragma unroll
      for (int d = 0; d < 8; d++) en[w][d] = ze[w][d] * inv;
    }
    float best[4]; int bidx[4];
    #pragma unroll
    for (int w = 0; w < 4; w++) { best[w] = -INFINITY; bidx[w] = 0; }
    #pragma unroll 4
    for (int r = 0; r < 16; r++) {
      int j = lane + (r << 6);
      float c0 = cbv[0][j], c1 = cbv[1][j], c2 = cbv[2][j], c3 = cbv[3][j];
      float c4 = cbv[4][j], c5 = cbv[5][j], c6 = cbv[6][j], c7 = cbv[7][j];
      float ti = cbs2[0][j], ns = cbs2[1][j];
      #pragma unroll
      for (int w = 0; w < 4; w++) {
        float dt = en[w][0] * c0;
        dt = fmaf(en[w][1], c1, dt); dt = fmaf(en[w][2], c2, dt);
        dt = fmaf(en[w][3], c3, dt); dt = fmaf(en[w][4], c4, dt);
        dt = fmaf(en[w][5], c5, dt); dt = fmaf(en[w][6], c6, dt);
        dt = fmaf(en[w][7], c7, dt);
        float s = fmaf(dt, ti, -ns);
        if (s > best[w]) { best[w] = s; bidx[w] = j; }
      }
    }
    #pragma unroll
    for (int w = 0; w < 4; w++) {
      #pragma unroll
      for (int off = 32; off; off >>= 1) {
        float so = __shfl_xor(best[w], off);
        int jo = __shfl_xor(bidx[w], off);
        if (so > best[w] || (so == best[w] && jo < bidx[w])) { best[w] = so; bidx[w] = jo; }
      }
    }
    int d = lane & 7;
    #pragma unroll
    for (int w = 0; w < 4; w++) {
      int jstar = bidx[w];
      int tokl = wid * 4 + w;
      int n = nb0 + tokl;
      float qd = cbv[d][jstar];
      float diff = ze[w][d] - qd;
      float sq = diff * diff;
      sq += __shfl_xor(sq, 1); sq += __shfl_xor(sq, 2); sq += __shfl_xor(sq, 4);
      if (lane == 0) lossLocal += sq;
      if (lane < 8) Qout[(size_t)n * 80 + i * 8 + lane] = qd;
      if (lane == 0) codesOut[(size_t)((n >> 11) * NQ + i) * TQ + (n & (TQ - 1))] = (float)jstar;
      if (i < NQ - 1) {
        int f = lane >> 3, d2 = lane & 7;
        int ip = i + 1 + f;
        if (ip < NQ) {
          int tri = (ip * (ip - 1)) / 2 + i;
          const float* prow = ptW + (size_t)tri * 65 + d2 * 8;
          float s = 0.f;
          #pragma unroll
          for (int dp = 0; dp < 8; dp++) s = fmaf(prow[dp], cbv[dp][jstar], s);
          est[tokl][ip * 8 + d2] -= s;
        }
      }
    }
  }
  if (lane == 0) lred[wid] = lossLocal;
  __syncthreads();
  if (tid == 0) {
    float s = ((lred[0] + lred[1]) + lred[2]) + lred[3];
    lossPart[blockIdx.x] = s;
  }
}

// ---------------- xfin + loss_fin merged (grid dim3(129,16)) ----------------
__global__ __launch_bounds__(256) void xfin_loss(const float* __restrict__ wx,
                                                 const float* __restrict__ Q,
                                                 const float* __restrict__ bup,
                                                 const float* __restrict__ lossPart,
                                                 float* __restrict__ xout,
                                                 float* __restrict__ lossOut) {
  const int tid = threadIdx.x;
  if (blockIdx.x == 128) {
    if (blockIdx.y != 0) return;
    __shared__ float s[256];
    float v = 0.f;
    for (int r = 0; r < 4; r++) v += lossPart[tid + r * 256];
    s[tid] = v;
    __syncthreads();
    for (int w = 128; w; w >>= 1) {
      if (tid < w) s[tid] += s[tid + w];
      __syncthreads();
    }
    if (tid == 0) {
      float total = s[0] / 131072.0f;
      lossOut[0] = total;
      lossOut[1] = total;
    }
    return;
  }
  __shared__ float Wxs[128][80];
  __shared__ float Qs[128][80];
  const int n0 = blockIdx.x * 128, m0 = blockIdx.y * 128;
  #pragma unroll
  for (int rep = 0; rep < 10; rep++) {
    int f = tid + rep * 256;
    *(float4*)&Wxs[0][f * 4] = *(const float4*)(wx + (size_t)m0 * 80 + f * 4);
    *(float4*)&Qs[0][f * 4] = *(const float4*)(Q + (size_t)n0 * 80 + f * 4);
  }
  __syncthreads();

  const int txn = tid & 15, tym = tid >> 4;
  float acc[8][8];
  #pragma unroll
  for (int i = 0; i < 8; i++)
    #pragma unroll
    for (int j = 0; j < 8; j++) acc[i][j] = 0.f;

  #pragma unroll 2
  for (int r4 = 0; r4 < 18; r4++) {
    float4 wv[8], qv[8];
    #pragma unroll
    for (int i = 0; i < 8; i++) wv[i] = *(const float4*)&Wxs[tym * 8 + i][r4 * 4];
    #pragma unroll
    for (int j = 0; j < 8; j++) qv[j] = *(const float4*)&Qs[txn * 8 + j][r4 * 4];
    #pragma unroll
    for (int i = 0; i < 8; i++)
      #pragma unroll
      for (int j = 0; j < 8; j++) {
        acc[i][j] = fmaf(wv[i].x, qv[j].x, acc[i][j]);
        acc[i][j] = fmaf(wv[i].y, qv[j].y, acc[i][j]);
        acc[i][j] = fmaf(wv[i].z, qv[j].z, acc[i][j]);
        acc[i][j] = fmaf(wv[i].w, qv[j].w, acc[i][j]);
      }
  }

  float bxv[8];
  #pragma unroll
  for (int mi = 0; mi < 8; mi++) {
    int mp = m0 + tym * 8 + mi;
    bxv[mi] = Wxs[tym * 8 + mi][72] + bup[(mp >> 2) * 2 + (mp & 1)];
  }
  #pragma unroll
  for (int cg = 0; cg < 2; cg++) {
    int mp0 = m0 + tym * 8 + cg * 4;
    int c = mp0 >> 2;
    #pragma unroll
    for (int j = 0; j < 8; j++) {
      int n = n0 + txn * 8 + j;
      int b = n >> 11, t = n & 2047;
      float4 sv = make_float4(acc[cg * 4 + 0][j] + bxv[cg * 4 + 0],
                              acc[cg * 4 + 1][j] + bxv[cg * 4 + 1],
                              acc[cg * 4 + 2][j] + bxv[cg * 4 + 2],
                              acc[cg * 4 + 3][j] + bxv[cg * 4 + 3]);
      *(float4*)&xout[((size_t)((b << 9) + c)) * 8192 + 4 * t] = sv;
    }
  }
}

// ---------------- launch ----------------
extern "C" void kernel_launch(void* const* d_in, const int* in_sizes, int n_in,
                              void* d_out, int out_size, void* d_ws, size_t ws_size,
                              hipStream_t stream) {
  const float* z      = (const float*)d_in[0];
  const float* down_w = (const float*)d_in[1];
  const float* down_b = (const float*)d_in[2];
  const float* up_w   = (const float*)d_in[3];
  const float* up_b   = (const float*)d_in[4];
  const float* in_v   = (const float*)d_in[5];
  const float* in_g   = (const float*)d_in[6];
  const float* in_b   = (const float*)d_in[7];
  const float* out_v  = (const float*)d_in[8];
  const float* out_g  = (const float*)d_in[9];
  const float* out_b  = (const float*)d_in[10];
  const float* codebooks = (const float*)d_in[11];
  float* ws = (float*)d_ws;
  float* xout = (float*)d_out;
  float* codesOut = xout + (size_t)8 * 512 * 8192;
  float* lossOut = codesOut + (size_t)8 * NQ * TQ;

  hipLaunchKernelGGL(prep_all1, dim3(718), dim3(256), 0, stream,
                     in_v, in_g, out_v, out_g, out_b, codebooks,
                     down_w, down_b, up_w, up_b, ws);
  hipLaunchKernelGGL(prep_all2, dim3(4818), dim3(256), 0, stream, in_b, out_b, ws);
  // fused down: x2 = W_d(3-split) @ zg + b_d
  hipLaunchKernelGGL(gemm_down, dim3(128, 4), dim3(256), 0, stream,
                     (const u16*)(ws + OFF_WDP), z, ws + OFF_BD, ws + OFF_X2);
  // RVQ (with in-block e0)
  hipLaunchKernelGGL(rvq_kernel, dim3(1024), dim3(256), 0, stream,
                     codebooks, ws + OFF_X2, ws + OFF_WINN,
                     ws + OFF_CBS, ws + OFF_PT, ws + OFF_BEFF,
                     ws + OFF_Q, codesOut, ws + OFF_LOSS);
  // x = Wx @ Q + bx  (+ loss finalize)
  hipLaunchKernelGGL(xfin_loss, dim3(129, 16), dim3(256), 0, stream,
                     ws + OFF_WX, ws + OFF_Q, ws + OFF_BUP, ws + OFF_LOSS,
                     xout, lossOut);
}

// Round 20
// 798.135 us; speedup vs baseline: 1.1532x; 1.1464x over previous
//
#include <hip/hip_runtime.h>
#include <math.h>

// FireflyVQ R20: revert R19's e0-fold (uncoalesced column walk cost 150us).
// Structure = R17 (780us proven) + R19's safe launch fusions (5 kernels).
// gemm_down R17-verbatim (277us), gemm_e0f restored, rvq reads e0t.
// All code-determining chains = R17 realization -> codes bit-exact.

using u16 = unsigned short;
typedef __attribute__((ext_vector_type(8))) short bf16x8;
typedef __attribute__((ext_vector_type(8))) u16 su16x8;
typedef __attribute__((ext_vector_type(4))) float f32x4;

constexpr int NQ = 9, CBS = 1024, CBD = 8;
constexpr int TQ = 2048;
constexpr int NTOK = 16384;
constexpr int APS = 1048576;   // u16 per W_d split plane (512*2048)
#define EPSN 1e-12f

// ---- ws layout (float offsets)
constexpr size_t OFF_X2    = 0;                  // [8][512][2048] fp32
constexpr size_t OFF_E0T   = 8388608;            // [16384][72]
constexpr size_t OFF_Q     = 9568256;            // [16384][80] n-major
constexpr size_t OFF_WD    = 10878976;           // W_d [512][2048] fp32
constexpr size_t OFF_WDP   = 11927552;           // 3 u16 planes of W_d
constexpr size_t OFF_WEFF  = 13500416;           // W_eff [2048][512] fp32
constexpr size_t OFF_WX    = 14548992;           // Wx [2048][80]
constexpr size_t OFF_WINN  = 14712832;           // [72][512]
constexpr size_t OFF_WOUTS = 14749696;           // WoutS2 [512][80]
constexpr size_t OFF_CBS   = 14790656;           // [9][2][1024]
constexpr size_t OFF_PT    = 14809088;           // 2340
constexpr size_t OFF_BEFF  = 14811428;           // 72
constexpr size_t OFF_BSUM  = 14811500;           // 512
constexpr size_t OFF_BD    = 14812012;           // 512
constexpr size_t OFF_BUP   = 14812524;           // [512][2]
constexpr size_t OFF_LOSS  = 14813548;           // 1024

// ---------------- K1: prep_small1 (blocks 0..205) + smallmm2 (206..717) ----------------
__global__ __launch_bounds__(256) void prep_all1(const float* __restrict__ in_v,
                                                 const float* __restrict__ in_g,
                                                 const float* __restrict__ out_v,
                                                 const float* __restrict__ out_g,
                                                 const float* __restrict__ out_b,
                                                 const float* __restrict__ codebooks,
                                                 const float* __restrict__ down_w,
                                                 const float* __restrict__ down_b,
                                                 const float* __restrict__ up_w,
                                                 const float* __restrict__ up_b,
                                                 float* __restrict__ ws) {
  int bid = blockIdx.x, tid = threadIdx.x;
  if (bid < 206) {
    int wid4 = tid >> 6, lane = tid & 63;
    if (bid < 18) {  // WinN rows (locked)
      int wid = bid * 4 + wid4;
      if (wid < 72) {
        const float* v = in_v + (size_t)wid * 512;
        float ss = 0.f;
        for (int c = lane; c < 512; c += 64) ss += v[c] * v[c];
        #pragma unroll
        for (int o = 32; o; o >>= 1) ss += __shfl_xor(ss, o);
        float sc = in_g[wid] / sqrtf(ss);
        float* dst = ws + OFF_WINN + (size_t)wid * 512;
        for (int c = lane; c < 512; c += 64) dst[c] = v[c] * sc;
      }
    } else if (bid < 36) {  // WoutS2 cols 0..71 (locked)
      int r = (bid - 18) * 256 + tid;
      if (r < 4608) {
        int i = r >> 9, c = r & 511;
        const float* v = out_v + (size_t)r * 8;
        float ss = 0.f;
        #pragma unroll
        for (int d = 0; d < 8; d++) ss += v[d] * v[d];
        float sc = out_g[r] / sqrtf(ss);
        float* dst = ws + OFF_WOUTS + (size_t)c * 80 + i * 8;
        #pragma unroll
        for (int d = 0; d < 8; d++) dst[d] = v[d] * sc;
      }
    } else if (bid < 72) {  // codebook scalars (locked)
      int r = (bid - 36) * 256 + tid;
      if (r < 9216) {
        int i = r >> 10, j = r & 1023;
        const float* v = codebooks + (size_t)r * 8;
        float ss = 0.f;
        #pragma unroll
        for (int d = 0; d < 8; d++) ss += v[d] * v[d];
        float nm = fmaxf(sqrtf(ss), EPSN);
        float nsq = 0.f;
        #pragma unroll
        for (int d = 0; d < 8; d++) { float cn = v[d] / nm; nsq += cn * cn; }
        ws[OFF_CBS + ((size_t)i * 2 + 0) * 1024 + j] = 2.0f / nm;
        ws[OFF_CBS + ((size_t)i * 2 + 1) * 1024 + j] = nsq;
      }
    } else if (bid < 74) {  // bsum + WoutS2 col 72..79 (locked)
      int c = (bid - 72) * 256 + tid;
      if (c < 512) {
        float s = 0.f;
        #pragma unroll
        for (int j = 0; j < 9; j++) s += out_b[j * 512 + c];
        ws[OFF_BSUM + c] = s;
        ws[OFF_WOUTS + (size_t)c * 80 + 72] = s;
        #pragma unroll
        for (int d = 73; d < 80; d++) ws[OFF_WOUTS + (size_t)c * 80 + d] = 0.f;
      }
    } else if (bid < 202) {  // b_d[o] (locked)
      int o = (bid - 74) * 4 + wid4;
      float s = 0.f;
      for (int m = lane; m < 512; m += 64) {
        float w0 = down_w[524288 + (size_t)o * 1024 + m * 2];
        float w1 = down_w[524288 + (size_t)o * 1024 + m * 2 + 1];
        s += (w0 + w1) * down_b[m];
      }
      #pragma unroll
      for (int off = 32; off; off >>= 1) s += __shfl_xor(s, off);
      if (lane == 0) ws[OFF_BD + o] = s + down_b[512 + o];
    } else {  // bup (x-only)
      int gw = (bid - 202) * 256 + tid;
      int c = gw >> 1, j2 = gw & 1;
      float s = 0.f;
      for (int m = 0; m < 512; m++)
        s += up_w[524288 + (size_t)m * 1024 + c * 2 + j2] * up_b[m];
      ws[OFF_BUP + gw] = s + up_b[512 + c];
    }
    return;
  }
  // ---- smallmm2 part
  __shared__ float As[32][68];
  __shared__ float Bs[32][68];
  const int bid2 = bid - 206;
  const int tx = tid & 15, ty = tid >> 4;
  const int b0 = (bid2 & 7) * 64, a0 = ((bid2 >> 3) & 7) * 64;
  const int zz = bid2 >> 6;
  const int which = zz >> 2, j = zz & 3;
  const int jh = j >> 1, jl = j & 1;
  const float* src = which ? up_w : down_w;
  float acc[4][4];
  #pragma unroll
  for (int i = 0; i < 4; i++)
    #pragma unroll
    for (int k = 0; k < 4; k++) acc[i][k] = 0.f;

  for (int k0 = 0; k0 < 512; k0 += 32) {
    #pragma unroll
    for (int rep = 0; rep < 8; rep++) {
      int f = tid + rep * 256;
      int aa = f >> 5, mm = f & 31;
      size_t ai = which ? (524288 + (size_t)(k0 + mm) * 1024 + (a0 + aa) * 2 + jl)
                        : (524288 + (size_t)(a0 + aa) * 1024 + (k0 + mm) * 2 + jh);
      As[mm][aa] = src[ai];
      int mm2 = f >> 6, bb = f & 63;
      size_t bi = which ? ((size_t)(b0 + bb) * 1024 + (k0 + mm2) * 2 + jh)
                        : ((size_t)(k0 + mm2) * 1024 + (b0 + bb) * 2 + jl);
      Bs[mm2][bb] = src[bi];
    }
    __syncthreads();
    #pragma unroll
    for (int kk = 0; kk < 32; kk++) {
      float av[4], bv[4];
      #pragma unroll
      for (int i = 0; i < 4; i++) av[i] = As[kk][ty * 4 + i];
      #pragma unroll
      for (int i = 0; i < 4; i++) bv[i] = Bs[kk][tx * 4 + i];
      #pragma unroll
      for (int i = 0; i < 4; i++)
        #pragma unroll
        for (int k = 0; k < 4; k++) acc[i][k] = fmaf(av[i], bv[k], acc[i][k]);
    }
    __syncthreads();
  }
  float* wd = ws + OFF_WD;
  float* weff = ws + OFF_WEFF;
  #pragma unroll
  for (int i = 0; i < 4; i++) {
    int a = a0 + ty * 4 + i;
    #pragma unroll
    for (int k = 0; k < 4; k++) {
      int b = b0 + tx * 4 + k;
      if (which) weff[((size_t)a * 4 + j) * 512 + b] = acc[i][k];
      else       wd[(size_t)a * 2048 + b * 4 + j] = acc[i][k];
    }
  }
}

// ---------------- K2: prep2 (blocks 0..593) + prep_split_wx (594..4817) ----------------
__global__ __launch_bounds__(256) void prep_all2(const float* __restrict__ in_b,
                                                 const float* __restrict__ out_b,
                                                 float* __restrict__ ws) {
  const int tid = threadIdx.x;
  if (blockIdx.x < 594) {  // prep2 (locked)
    int gw = blockIdx.x * 4 + (tid >> 6), lane = tid & 63;
    const float* WinN = ws + OFF_WINN;
    const float* WoutS = ws + OFF_WOUTS;
    if (gw < 2304) {
      int tri = gw >> 6, dd = gw & 63;
      int ip = 1;
      while (tri >= ip * (ip + 1) / 2) ip++;
      int i = tri - ip * (ip - 1) / 2;
      int d = dd >> 3, dp = dd & 7;
      const float* a = WinN + (size_t)(ip * 8 + d) * 512;
      float s = 0.f;
      for (int c = lane; c < 512; c += 64) s += a[c] * WoutS[(size_t)c * 80 + i * 8 + dp];
      #pragma unroll
      for (int o = 32; o; o >>= 1) s += __shfl_xor(s, o);
      if (lane == 0) ws[OFF_PT + (size_t)tri * 65 + dd] = s;
    } else if (gw < 2376) {
      int r = gw - 2304;
      int i = r >> 3;
      const float* a = WinN + (size_t)r * 512;
      float s = 0.f;
      for (int c = lane; c < 512; c += 64) {
        float ob = 0.f;
        for (int j = 0; j < i; j++) ob += out_b[j * 512 + c];
        s += a[c] * ob;
      }
      #pragma unroll
      for (int o = 32; o; o >>= 1) s += __shfl_xor(s, o);
      if (lane == 0) ws[OFF_BEFF + r] = in_b[r] - s;
    }
    return;
  }
  const int bid2 = blockIdx.x - 594;
  if (bid2 < 4096) {  // wdsplit
    int idx = bid2 * 256 + tid;
    const float* wd = ws + OFF_WD;
    u16* wdp = (u16*)(ws + OFF_WDP);
    float v = wd[idx];
    unsigned u = __float_as_uint(v);
    wdp[idx] = (u16)(u >> 16);
    float r = v - __uint_as_float(u & 0xFFFF0000u);
    unsigned ur = __float_as_uint(r);
    wdp[APS + idx] = (u16)(ur >> 16);
    float r2 = r - __uint_as_float(ur & 0xFFFF0000u);
    wdp[2 * APS + idx] = (u16)(__float_as_uint(r2) >> 16);
    return;
  }
  // prep_wx
  __shared__ float Wes[16][512];
  __shared__ float WSs[64][80];
  const float* weff = ws + OFF_WEFF;
  const float* wouts = ws + OFF_WOUTS;
  float* wx = ws + OFF_WX;
  const int m0 = (bid2 - 4096) * 16;
  #pragma unroll
  for (int rep = 0; rep < 32; rep++) {
    int f = tid + rep * 256;
    Wes[f >> 9][f & 511] = weff[(size_t)(m0 + (f >> 9)) * 512 + (f & 511)];
  }
  const int rowq = tid >> 4, rq = tid & 15;
  float accs[5] = {0.f, 0.f, 0.f, 0.f, 0.f};
  for (int k0 = 0; k0 < 512; k0 += 64) {
    __syncthreads();
    #pragma unroll
    for (int rep = 0; rep < 20; rep++) {
      int f = tid + rep * 256;
      int kk = f / 80, col = f % 80;
      WSs[kk][col] = wouts[(size_t)(k0 + kk) * 80 + col];
    }
    __syncthreads();
    #pragma unroll 4
    for (int kk = 0; kk < 64; kk++) {
      float we = Wes[rowq][k0 + kk];
      #pragma unroll
      for (int s = 0; s < 5; s++) accs[s] = fmaf(we, WSs[kk][rq + 16 * s], accs[s]);
    }
  }
  #pragma unroll
  for (int s = 0; s < 5; s++) {
    int r = rq + 16 * s;
    if (r < 73) wx[(size_t)(m0 + rowq) * 80 + r] = accs[s];
  }
  if (tid < 112) {
    int row = tid / 7, col = 73 + tid % 7;
    wx[(size_t)(m0 + row) * 80 + col] = 0.f;
  }
}

// ---------------- gemm_down (R17 verbatim: 128x128, 4 waves, 277us) ----------------
__global__ __launch_bounds__(256) void gemm_down(const u16* __restrict__ Ap,
                                                 const float* __restrict__ z,
                                                 const float* __restrict__ bias,
                                                 float* __restrict__ Out) {
  constexpr int NS = 3, K = 2048;
  __shared__ u16 Bp[2][NS][128][32];
  const int tid = threadIdx.x;
  const int w = tid >> 6, l = tid & 63;
  const int g = l >> 4, li = l & 15;
  const int wr = w >> 1, wc = w & 1;
  const int n0 = blockIdx.x * 128, m0 = blockIdx.y * 128;
  const int nn = tid & 127, kw = tid >> 7;
  const int bb = n0 >> 11;
  const int tb = (n0 & 2047) + nn;

  f32x4 acc[4][4];
  #pragma unroll
  for (int a = 0; a < 4; a++)
    #pragma unroll
    for (int b = 0; b < 4; b++) acc[a][b] = (f32x4){0.f, 0.f, 0.f, 0.f};

  float pvA[16], pvB[16];

#define LOADB(PV, K0)                                                           \
  {                                                                             \
    int c0_ = ((K0) >> 2) + kw * 4;                                             \
    _Pragma("unroll")                                                           \
    for (int cc_ = 0; cc_ < 4; ++cc_)                                           \
      *(float4*)&PV[4 * cc_] =                                                  \
          *(const float4*)(z + ((size_t)(bb * 512 + c0_ + cc_) << 13) + 4 * tb);\
  }

  const int sw = (nn >> 1) & 3;
  const int c0 = ((2 * kw) ^ sw) << 3, c1 = ((2 * kw + 1) ^ sw) << 3;

#define STAGE(BUF, PV)                                                          \
  {                                                                             \
    su16x8 pa_[NS], pb_[NS];                                                    \
    _Pragma("unroll")                                                           \
    for (int j_ = 0; j_ < 8; ++j_) {                                            \
      {                                                                         \
        float v_ = PV[j_];                                                      \
        unsigned u_ = __float_as_uint(v_);                                      \
        pa_[0][j_] = (u16)(u_ >> 16);                                           \
        float r_ = v_ - __uint_as_float(u_ & 0xFFFF0000u);                      \
        unsigned ur_ = __float_as_uint(r_);                                     \
        pa_[1][j_] = (u16)(ur_ >> 16);                                          \
        float r2_ = r_ - __uint_as_float(ur_ & 0xFFFF0000u);                    \
        pa_[2][j_] = (u16)(__float_as_uint(r2_) >> 16);                         \
      }                                                                         \
      {                                                                         \
        float v_ = PV[8 + j_];                                                  \
        unsigned u_ = __float_as_uint(v_);                                      \
        pb_[0][j_] = (u16)(u_ >> 16);                                           \
        float r_ = v_ - __uint_as_float(u_ & 0xFFFF0000u);                      \
        unsigned ur_ = __float_as_uint(r_);                                     \
        pb_[1][j_] = (u16)(ur_ >> 16);                                          \
        float r2_ = r_ - __uint_as_float(ur_ & 0xFFFF0000u);                    \
        pb_[2][j_] = (u16)(__float_as_uint(r2_) >> 16);                         \
      }                                                                         \
    }                                                                           \
    _Pragma("unroll")                                                           \
    for (int p_ = 0; p_ < NS; ++p_) {                                           \
      *(su16x8*)&Bp[BUF][p_][nn][c0] = pa_[p_];                                 \
      *(su16x8*)&Bp[BUF][p_][nn][c1] = pb_[p_];                                 \
    }                                                                           \
  }

#define COMPUTE(BUF, K0)                                                        \
  {                                                                             \
    bf16x8 bfr_[4][NS];                                                         \
    _Pragma("unroll")                                                           \
    for (int fn_ = 0; fn_ < 4; ++fn_) {                                         \
      int row_ = wc * 64 + fn_ * 16 + li;                                       \
      int cs_ = ((g ^ ((row_ >> 1) & 3)) << 3);                                 \
      _Pragma("unroll")                                                         \
      for (int q_ = 0; q_ < NS; ++q_)                                           \
        bfr_[fn_][q_] = *(const bf16x8*)&Bp[BUF][q_][row_][cs_];                \
    }                                                                           \
    const u16* arow_ = Ap + (size_t)(m0 + wr * 64 + li) * K + (K0) + g * 8;     \
    _Pragma("unroll")                                                           \
    for (int fm_ = 0; fm_ < 4; ++fm_) {                                         \
      bf16x8 afr_[NS];                                                          \
      _Pragma("unroll")                                                         \
      for (int p_ = 0; p_ < NS; ++p_)                                           \
        afr_[p_] = *(const bf16x8*)(arow_ + (size_t)p_ * APS + (size_t)fm_ * 16 * K); \
      _Pragma("unroll")                                                         \
      for (int fn_ = 0; fn_ < 4; ++fn_) {                                       \
        f32x4 a_ = acc[fm_][fn_];                                               \
        a_ = __builtin_amdgcn_mfma_f32_16x16x32_bf16(afr_[2], bfr_[fn_][0], a_, 0, 0, 0); \
        a_ = __builtin_amdgcn_mfma_f32_16x16x32_bf16(afr_[1], bfr_[fn_][1], a_, 0, 0, 0); \
        a_ = __builtin_amdgcn_mfma_f32_16x16x32_bf16(afr_[0], bfr_[fn_][2], a_, 0, 0, 0); \
        a_ = __builtin_amdgcn_mfma_f32_16x16x32_bf16(afr_[1], bfr_[fn_][0], a_, 0, 0, 0); \
        a_ = __builtin_amdgcn_mfma_f32_16x16x32_bf16(afr_[0], bfr_[fn_][1], a_, 0, 0, 0); \
        a_ = __builtin_amdgcn_mfma_f32_16x16x32_bf16(afr_[0], bfr_[fn_][0], a_, 0, 0, 0); \
        acc[fm_][fn_] = a_;                                                     \
      }                                                                         \
    }                                                                           \
  }

  LOADB(pvA, 0)
  LOADB(pvB, 32)
  STAGE(0, pvA)
  LOADB(pvA, 64)
  __syncthreads();

  for (int k0 = 0; k0 < K; k0 += 64) {
    STAGE(1, pvB)
    if (k0 + 96 < K) { LOADB(pvB, k0 + 96) }
    COMPUTE(0, k0)
    __syncthreads();
    if (k0 + 64 < K) { STAGE(0, pvA) }
    if (k0 + 128 < K) { LOADB(pvA, k0 + 128) }
    COMPUTE(1, k0 + 32)
    __syncthreads();
  }
#undef LOADB
#undef STAGE
#undef COMPUTE

  const int mb = m0 + wr * 64 + g * 4;
  const int nb = n0 + wc * 64 + li;
  #pragma unroll
  for (int fn = 0; fn < 4; ++fn) {
    int n = nb + fn * 16;
    int b = n >> 11, t = n & 2047;
    #pragma unroll
    for (int fm = 0; fm < 4; ++fm)
      #pragma unroll
      for (int r = 0; r < 4; ++r) {
        int o = mb + fm * 16 + r;
        Out[((size_t)((b << 9) + o)) * 2048 + t] = acc[fm][fn][r] + bias[o];
      }
  }
}

// ---------------- gemm_e0f (R14 verbatim): e0t = WinN @ x2, BN=64 ----------------
__global__ __launch_bounds__(256) void gemm_e0f(const float* __restrict__ A,
                                                const float* __restrict__ Bsrc,
                                                float* __restrict__ e0t) {
  constexpr int M = 72, K = 512, Tt = 2048;
  __shared__ float As[16][132];
  __shared__ float Bs[16][68];
  int tid = threadIdx.x;
  int tx = tid & 7, ty = tid >> 3;
  int n0 = blockIdx.x * 64;
  int b = n0 / Tt, t0 = n0 % Tt;
  float acc[4][8];
  #pragma unroll
  for (int i = 0; i < 4; i++)
    #pragma unroll
    for (int j = 0; j < 8; j++) acc[i][j] = 0.f;

  for (int k0 = 0; k0 < K; k0 += 16) {
    #pragma unroll
    for (int rep = 0; rep < 2; rep++) {
      int f = tid + rep * 256;
      int row = f >> 2, c4 = (f & 3) << 2;
      int m = row, k = k0 + c4;
      float4 v = make_float4(0.f, 0.f, 0.f, 0.f);
      if (m < M) v = *(const float4*)(A + (size_t)m * K + k);
      As[c4 + 0][row] = v.x; As[c4 + 1][row] = v.y;
      As[c4 + 2][row] = v.z; As[c4 + 3][row] = v.w;
    }
    {
      int kk = tid >> 4, n4 = (tid & 15) << 2;
      float4 v = *(const float4*)(Bsrc + ((size_t)(b * K + k0 + kk)) * Tt + t0 + n4);
      *(float4*)&Bs[kk][n4] = v;
    }
    __syncthreads();
    #pragma unroll
    for (int kk = 0; kk < 16; kk++) {
      float a[4], bb[8];
      #pragma unroll
      for (int i = 0; i < 4; i++) a[i] = As[kk][ty * 4 + i];
      *(float4*)&bb[0] = *(float4*)&Bs[kk][tx * 8];
      *(float4*)&bb[4] = *(float4*)&Bs[kk][tx * 8 + 4];
      #pragma unroll
      for (int i = 0; i < 4; i++)
        #pragma unroll
        for (int j = 0; j < 8; j++) acc[i][j] = fmaf(a[i], bb[j], acc[i][j]);
    }
    __syncthreads();
  }
  #pragma unroll
  for (int j = 0; j < 8; j++) {
    int n = n0 + tx * 8 + j;
    #pragma unroll
    for (int i = 0; i < 4; i++) {
      int m = ty * 4 + i;
      if (m < M) e0t[(size_t)n * M + m] = acc[i][j];
    }
  }
}

// ---------------- RVQ core (R17 verbatim: e0t input, Pt global, Q n-major) ----------------
__global__ __launch_bounds__(256) void rvq_kernel(const float* __restrict__ codebooks,
                                                  const float* __restrict__ e0t,
                                                  const float* __restrict__ cbsW,
                                                  const float* __restrict__ ptW,
                                                  const float* __restrict__ beffW,
                                                  float* __restrict__ Qout,
                                                  float* __restrict__ codesOut,
                                                  float* __restrict__ lossPart) {
  __shared__ float cbv[8][1024];
  __shared__ float cbs2[2][1024];
  __shared__ float est[16][72];
  __shared__ float lred[4];
  int tid = threadIdx.x, wid = tid >> 6, lane = tid & 63;
  int nb0 = blockIdx.x * 16;
  for (int idx = tid; idx < 16 * 72; idx += 256)
    est[idx / 72][idx % 72] = e0t[(size_t)nb0 * 72 + idx] + beffW[idx % 72];
  float lossLocal = 0.f;

  for (int i = 0; i < NQ; i++) {
    __syncthreads();
    const float* cbg = codebooks + (size_t)i * CBS * CBD;
    for (int lin = tid; lin < 2048; lin += 256) {
      int j = lin >> 1, half = (lin & 1) << 2;
      float4 v = *(const float4*)(cbg + (size_t)j * 8 + half);
      cbv[half + 0][j] = v.x; cbv[half + 1][j] = v.y;
      cbv[half + 2][j] = v.z; cbv[half + 3][j] = v.w;
    }
    for (int lin = tid; lin < 1024; lin += 256) {
      cbs2[0][lin] = cbsW[((size_t)i * 2 + 0) * 1024 + lin];
      cbs2[1][lin] = cbsW[((size_t)i * 2 + 1) * 1024 + lin];
    }
    __syncthreads();

    float ze[4][8], en[4][8];
    #pragma unroll
    for (int w = 0; w < 4; w++) {
      int tokl = wid * 4 + w;
      float ss = 0.f;
      #pragma unroll
      for (int d = 0; d < 8; d++) { float v = est[tokl][i * 8 + d]; ze[w][d] = v; ss += v * v; }
      float inv = 1.0f / fmaxf(sqrtf(ss), EPSN);
      #pragma unroll
      for (int d = 0; d < 8; d++) en[w][d] = ze[w][d] * inv;
    }
    float best[4]; int bidx[4];
    #pragma unroll
    for (int w = 0; w < 4; w++) { best[w] = -INFINITY; bidx[w] = 0; }
    #pragma unroll 4
    for (int r = 0; r < 16; r++) {
      int j = lane + (r << 6);
      float c0 = cbv[0][j], c1 = cbv[1][j], c2 = cbv[2][j], c3 = cbv[3][j];
      float c4 = cbv[4][j], c5 = cbv[5][j], c6 = cbv[6][j], c7 = cbv[7][j];
      float ti = cbs2[0][j], ns = cbs2[1][j];
      #pragma unroll
      for (int w = 0; w < 4; w++) {
        float dt = en[w][0] * c0;
        dt = fmaf(en[w][1], c1, dt); dt = fmaf(en[w][2], c2, dt);
        dt = fmaf(en[w][3], c3, dt); dt = fmaf(en[w][4], c4, dt);
        dt = fmaf(en[w][5], c5, dt); dt = fmaf(en[w][6], c6, dt);
        dt = fmaf(en[w][7], c7, dt);
        float s = fmaf(dt, ti, -ns);
        if (s > best[w]) { best[w] = s; bidx[w] = j; }
      }
    }
    #pragma unroll
    for (int w = 0; w < 4; w++) {
      #pragma unroll
      for (int off = 32; off; off >>= 1) {
        float so = __shfl_xor(best[w], off);
        int jo = __shfl_xor(bidx[w], off);
        if (so > best[w] || (so == best[w] && jo < bidx[w])) { best[w] = so; bidx[w] = jo; }
      }
    }
    int d = lane & 7;
    #pragma unroll
    for (int w = 0; w < 4; w++) {
      int jstar = bidx[w];
      int tokl = wid * 4 + w;
      int n = nb0 + tokl;
      float qd = cbv[d][jstar];
      float diff = ze[w][d] - qd;
      float sq = diff * diff;
      sq += __shfl_xor(sq, 1); sq += __shfl_xor(sq, 2); sq += __shfl_xor(sq, 4);
      if (lane == 0) lossLocal += sq;
      if (lane < 8) Qout[(size_t)n * 80 + i * 8 + lane] = qd;
      if (lane == 0) codesOut[(size_t)((n >> 11) * NQ + i) * TQ + (n & (TQ - 1))] = (float)jstar;
      if (i < NQ - 1) {
        int f = lane >> 3, d2 = lane & 7;
        int ip = i + 1 + f;
        if (ip < NQ) {
          int tri = (ip * (ip - 1)) / 2 + i;
          const float* prow = ptW + (size_t)tri * 65 + d2 * 8;
          float s = 0.f;
          #pragma unroll
          for (int dp = 0; dp < 8; dp++) s = fmaf(prow[dp], cbv[dp][jstar], s);
          est[tokl][ip * 8 + d2] -= s;
        }
      }
    }
  }
  if (lane == 0) lred[wid] = lossLocal;
  __syncthreads();
  if (tid == 0) {
    float s = ((lred[0] + lred[1]) + lred[2]) + lred[3];
    lossPart[blockIdx.x] = s;
  }
}

// ---------------- xfin + loss_fin merged (grid dim3(129,16)) ----------------
__global__ __launch_bounds__(256) void xfin_loss(const float* __restrict__ wx,
                                                 const float* __restrict__ Q,
                                                 const float* __restrict__ bup,
                                                 const float* __restrict__ lossPart,
                                                 float* __restrict__ xout,
                                                 float* __restrict__ lossOut) {
  const int tid = threadIdx.x;
  if (blockIdx.x == 128) {
    if (blockIdx.y != 0) return;
    __shared__ float s[256];
    float v = 0.f;
    for (int r = 0; r < 4; r++) v += lossPart[tid + r * 256];
    s[tid] = v;
    __syncthreads();
    for (int w = 128; w; w >>= 1) {
      if (tid < w) s[tid] += s[tid + w];
      __syncthreads();
    }
    if (tid == 0) {
      float total = s[0] / 131072.0f;
      lossOut[0] = total;
      lossOut[1] = total;
    }
    return;
  }
  __shared__ float Wxs[128][80];
  __shared__ float Qs[128][80];
  const int n0 = blockIdx.x * 128, m0 = blockIdx.y * 128;
  #pragma unroll
  for (int rep = 0; rep < 10; rep++) {
    int f = tid + rep * 256;
    *(float4*)&Wxs[0][f * 4] = *(const float4*)(wx + (size_t)m0 * 80 + f * 4);
    *(float4*)&Qs[0][f * 4] = *(const float4*)(Q + (size_t)n0 * 80 + f * 4);
  }
  __syncthreads();

  const int txn = tid & 15, tym = tid >> 4;
  float acc[8][8];
  #pragma unroll
  for (int i = 0; i < 8; i++)
    #pragma unroll
    for (int j = 0; j < 8; j++) acc[i][j] = 0.f;

  #pragma unroll 2
  for (int r4 = 0; r4 < 18; r4++) {
    float4 wv[8], qv[8];
    #pragma unroll
    for (int i = 0; i < 8; i++) wv[i] = *(const float4*)&Wxs[tym * 8 + i][r4 * 4];
    #pragma unroll
    for (int j = 0; j < 8; j++) qv[j] = *(const float4*)&Qs[txn * 8 + j][r4 * 4];
    #pragma unroll
    for (int i = 0; i < 8; i++)
      #pragma unroll
      for (int j = 0; j < 8; j++) {
        acc[i][j] = fmaf(wv[i].x, qv[j].x, acc[i][j]);
        acc[i][j] = fmaf(wv[i].y, qv[j].y, acc[i][j]);
        acc[i][j] = fmaf(wv[i].z, qv[j].z, acc[i][j]);
        acc[i][j] = fmaf(wv[i].w, qv[j].w, acc[i][j]);
      }
  }

  float bxv[8];
  #pragma unroll
  for (int mi = 0; mi < 8; mi++) {
    int mp = m0 + tym * 8 + mi;
    bxv[mi] = Wxs[tym * 8 + mi][72] + bup[(mp >> 2) * 2 + (mp & 1)];
  }
  #pragma unroll
  for (int cg = 0; cg < 2; cg++) {
    int mp0 = m0 + tym * 8 + cg * 4;
    int c = mp0 >> 2;
    #pragma unroll
    for (int j = 0; j < 8; j++) {
      int n = n0 + txn * 8 + j;
      int b = n >> 11, t = n & 2047;
      float4 sv = make_float4(acc[cg * 4 + 0][j] + bxv[cg * 4 + 0],
                              acc[cg * 4 + 1][j] + bxv[cg * 4 + 1],
                              acc[cg * 4 + 2][j] + bxv[cg * 4 + 2],
                              acc[cg * 4 + 3][j] + bxv[cg * 4 + 3]);
      *(float4*)&xout[((size_t)((b << 9) + c)) * 8192 + 4 * t] = sv;
    }
  }
}

// ---------------- launch ----------------
extern "C" void kernel_launch(void* const* d_in, const int* in_sizes, int n_in,
                              void* d_out, int out_size, void* d_ws, size_t ws_size,
                              hipStream_t stream) {
  const float* z      = (const float*)d_in[0];
  const float* down_w = (const float*)d_in[1];
  const float* down_b = (const float*)d_in[2];
  const float* up_w   = (const float*)d_in[3];
  const float* up_b   = (const float*)d_in[4];
  const float* in_v   = (const float*)d_in[5];
  const float* in_g   = (const float*)d_in[6];
  const float* in_b   = (const float*)d_in[7];
  const float* out_v  = (const float*)d_in[8];
  const float* out_g  = (const float*)d_in[9];
  const float* out_b  = (const float*)d_in[10];
  const float* codebooks = (const float*)d_in[11];
  float* ws = (float*)d_ws;
  float* xout = (float*)d_out;
  float* codesOut = xout + (size_t)8 * 512 * 8192;
  float* lossOut = codesOut + (size_t)8 * NQ * TQ;

  hipLaunchKernelGGL(prep_all1, dim3(718), dim3(256), 0, stream,
                     in_v, in_g, out_v, out_g, out_b, codebooks,
                     down_w, down_b, up_w, up_b, ws);
  hipLaunchKernelGGL(prep_all2, dim3(4818), dim3(256), 0, stream, in_b, out_b, ws);
  // fused down: x2 = W_d(3-split) @ zg + b_d
  hipLaunchKernelGGL(gemm_down, dim3(128, 4), dim3(256), 0, stream,
                     (const u16*)(ws + OFF_WDP), z, ws + OFF_BD, ws + OFF_X2);
  // e0t = WinN @ x2 (full-chip)
  hipLaunchKernelGGL(gemm_e0f, dim3(256), dim3(256), 0, stream,
                     ws + OFF_WINN, ws + OFF_X2, ws + OFF_E0T);
  // RVQ
  hipLaunchKernelGGL(rvq_kernel, dim3(1024), dim3(256), 0, stream,
                     codebooks, ws + OFF_E0T, ws + OFF_CBS, ws + OFF_PT, ws + OFF_BEFF,
                     ws + OFF_Q, codesOut, ws + OFF_LOSS);
  // x = Wx @ Q + bx  (+ loss finalize)
  hipLaunchKernelGGL(xfin_loss, dim3(129, 16), dim3(256), 0, stream,
                     ws + OFF_WX, ws + OFF_Q, ws + OFF_BUP, ws + OFF_LOSS,
                     xout, lossOut);
}

// Round 21
// 787.380 us; speedup vs baseline: 1.1690x; 1.0137x over previous
//
#include <hip/hip_runtime.h>
#include <math.h>

// FireflyVQ R21: R20 structure; rvq widened to 32 tokens/block (512 thr,
// 8 waves, grid 512) -> halves per-chip codebook staging + barrier cost.
// Per-token chains op-identical -> codes bit-exact. Loss partials 512.

using u16 = unsigned short;
typedef __attribute__((ext_vector_type(8))) short bf16x8;
typedef __attribute__((ext_vector_type(8))) u16 su16x8;
typedef __attribute__((ext_vector_type(4))) float f32x4;

constexpr int NQ = 9, CBS = 1024, CBD = 8;
constexpr int TQ = 2048;
constexpr int NTOK = 16384;
constexpr int APS = 1048576;   // u16 per W_d split plane (512*2048)
#define EPSN 1e-12f

// ---- ws layout (float offsets)
constexpr size_t OFF_X2    = 0;                  // [8][512][2048] fp32
constexpr size_t OFF_E0T   = 8388608;            // [16384][72]
constexpr size_t OFF_Q     = 9568256;            // [16384][80] n-major
constexpr size_t OFF_WD    = 10878976;           // W_d [512][2048] fp32
constexpr size_t OFF_WDP   = 11927552;           // 3 u16 planes of W_d
constexpr size_t OFF_WEFF  = 13500416;           // W_eff [2048][512] fp32
constexpr size_t OFF_WX    = 14548992;           // Wx [2048][80]
constexpr size_t OFF_WINN  = 14712832;           // [72][512]
constexpr size_t OFF_WOUTS = 14749696;           // WoutS2 [512][80]
constexpr size_t OFF_CBS   = 14790656;           // [9][2][1024]
constexpr size_t OFF_PT    = 14809088;           // 2340
constexpr size_t OFF_BEFF  = 14811428;           // 72
constexpr size_t OFF_BSUM  = 14811500;           // 512
constexpr size_t OFF_BD    = 14812012;           // 512
constexpr size_t OFF_BUP   = 14812524;           // [512][2]
constexpr size_t OFF_LOSS  = 14813548;           // 512 partials

// ---------------- K1: prep_small1 (blocks 0..205) + smallmm2 (206..717) ----------------
__global__ __launch_bounds__(256) void prep_all1(const float* __restrict__ in_v,
                                                 const float* __restrict__ in_g,
                                                 const float* __restrict__ out_v,
                                                 const float* __restrict__ out_g,
                                                 const float* __restrict__ out_b,
                                                 const float* __restrict__ codebooks,
                                                 const float* __restrict__ down_w,
                                                 const float* __restrict__ down_b,
                                                 const float* __restrict__ up_w,
                                                 const float* __restrict__ up_b,
                                                 float* __restrict__ ws) {
  int bid = blockIdx.x, tid = threadIdx.x;
  if (bid < 206) {
    int wid4 = tid >> 6, lane = tid & 63;
    if (bid < 18) {  // WinN rows (locked)
      int wid = bid * 4 + wid4;
      if (wid < 72) {
        const float* v = in_v + (size_t)wid * 512;
        float ss = 0.f;
        for (int c = lane; c < 512; c += 64) ss += v[c] * v[c];
        #pragma unroll
        for (int o = 32; o; o >>= 1) ss += __shfl_xor(ss, o);
        float sc = in_g[wid] / sqrtf(ss);
        float* dst = ws + OFF_WINN + (size_t)wid * 512;
        for (int c = lane; c < 512; c += 64) dst[c] = v[c] * sc;
      }
    } else if (bid < 36) {  // WoutS2 cols 0..71 (locked)
      int r = (bid - 18) * 256 + tid;
      if (r < 4608) {
        int i = r >> 9, c = r & 511;
        const float* v = out_v + (size_t)r * 8;
        float ss = 0.f;
        #pragma unroll
        for (int d = 0; d < 8; d++) ss += v[d] * v[d];
        float sc = out_g[r] / sqrtf(ss);
        float* dst = ws + OFF_WOUTS + (size_t)c * 80 + i * 8;
        #pragma unroll
        for (int d = 0; d < 8; d++) dst[d] = v[d] * sc;
      }
    } else if (bid < 72) {  // codebook scalars (locked)
      int r = (bid - 36) * 256 + tid;
      if (r < 9216) {
        int i = r >> 10, j = r & 1023;
        const float* v = codebooks + (size_t)r * 8;
        float ss = 0.f;
        #pragma unroll
        for (int d = 0; d < 8; d++) ss += v[d] * v[d];
        float nm = fmaxf(sqrtf(ss), EPSN);
        float nsq = 0.f;
        #pragma unroll
        for (int d = 0; d < 8; d++) { float cn = v[d] / nm; nsq += cn * cn; }
        ws[OFF_CBS + ((size_t)i * 2 + 0) * 1024 + j] = 2.0f / nm;
        ws[OFF_CBS + ((size_t)i * 2 + 1) * 1024 + j] = nsq;
      }
    } else if (bid < 74) {  // bsum + WoutS2 col 72..79 (locked)
      int c = (bid - 72) * 256 + tid;
      if (c < 512) {
        float s = 0.f;
        #pragma unroll
        for (int j = 0; j < 9; j++) s += out_b[j * 512 + c];
        ws[OFF_BSUM + c] = s;
        ws[OFF_WOUTS + (size_t)c * 80 + 72] = s;
        #pragma unroll
        for (int d = 73; d < 80; d++) ws[OFF_WOUTS + (size_t)c * 80 + d] = 0.f;
      }
    } else if (bid < 202) {  // b_d[o] (locked)
      int o = (bid - 74) * 4 + wid4;
      float s = 0.f;
      for (int m = lane; m < 512; m += 64) {
        float w0 = down_w[524288 + (size_t)o * 1024 + m * 2];
        float w1 = down_w[524288 + (size_t)o * 1024 + m * 2 + 1];
        s += (w0 + w1) * down_b[m];
      }
      #pragma unroll
      for (int off = 32; off; off >>= 1) s += __shfl_xor(s, off);
      if (lane == 0) ws[OFF_BD + o] = s + down_b[512 + o];
    } else {  // bup (x-only)
      int gw = (bid - 202) * 256 + tid;
      int c = gw >> 1, j2 = gw & 1;
      float s = 0.f;
      for (int m = 0; m < 512; m++)
        s += up_w[524288 + (size_t)m * 1024 + c * 2 + j2] * up_b[m];
      ws[OFF_BUP + gw] = s + up_b[512 + c];
    }
    return;
  }
  // ---- smallmm2 part
  __shared__ float As[32][68];
  __shared__ float Bs[32][68];
  const int bid2 = bid - 206;
  const int tx = tid & 15, ty = tid >> 4;
  const int b0 = (bid2 & 7) * 64, a0 = ((bid2 >> 3) & 7) * 64;
  const int zz = bid2 >> 6;
  const int which = zz >> 2, j = zz & 3;
  const int jh = j >> 1, jl = j & 1;
  const float* src = which ? up_w : down_w;
  float acc[4][4];
  #pragma unroll
  for (int i = 0; i < 4; i++)
    #pragma unroll
    for (int k = 0; k < 4; k++) acc[i][k] = 0.f;

  for (int k0 = 0; k0 < 512; k0 += 32) {
    #pragma unroll
    for (int rep = 0; rep < 8; rep++) {
      int f = tid + rep * 256;
      int aa = f >> 5, mm = f & 31;
      size_t ai = which ? (524288 + (size_t)(k0 + mm) * 1024 + (a0 + aa) * 2 + jl)
                        : (524288 + (size_t)(a0 + aa) * 1024 + (k0 + mm) * 2 + jh);
      As[mm][aa] = src[ai];
      int mm2 = f >> 6, bb = f & 63;
      size_t bi = which ? ((size_t)(b0 + bb) * 1024 + (k0 + mm2) * 2 + jh)
                        : ((size_t)(k0 + mm2) * 1024 + (b0 + bb) * 2 + jl);
      Bs[mm2][bb] = src[bi];
    }
    __syncthreads();
    #pragma unroll
    for (int kk = 0; kk < 32; kk++) {
      float av[4], bv[4];
      #pragma unroll
      for (int i = 0; i < 4; i++) av[i] = As[kk][ty * 4 + i];
      #pragma unroll
      for (int i = 0; i < 4; i++) bv[i] = Bs[kk][tx * 4 + i];
      #pragma unroll
      for (int i = 0; i < 4; i++)
        #pragma unroll
        for (int k = 0; k < 4; k++) acc[i][k] = fmaf(av[i], bv[k], acc[i][k]);
    }
    __syncthreads();
  }
  float* wd = ws + OFF_WD;
  float* weff = ws + OFF_WEFF;
  #pragma unroll
  for (int i = 0; i < 4; i++) {
    int a = a0 + ty * 4 + i;
    #pragma unroll
    for (int k = 0; k < 4; k++) {
      int b = b0 + tx * 4 + k;
      if (which) weff[((size_t)a * 4 + j) * 512 + b] = acc[i][k];
      else       wd[(size_t)a * 2048 + b * 4 + j] = acc[i][k];
    }
  }
}

// ---------------- K2: prep2 (blocks 0..593) + prep_split_wx (594..4817) ----------------
__global__ __launch_bounds__(256) void prep_all2(const float* __restrict__ in_b,
                                                 const float* __restrict__ out_b,
                                                 float* __restrict__ ws) {
  const int tid = threadIdx.x;
  if (blockIdx.x < 594) {  // prep2 (locked)
    int gw = blockIdx.x * 4 + (tid >> 6), lane = tid & 63;
    const float* WinN = ws + OFF_WINN;
    const float* WoutS = ws + OFF_WOUTS;
    if (gw < 2304) {
      int tri = gw >> 6, dd = gw & 63;
      int ip = 1;
      while (tri >= ip * (ip + 1) / 2) ip++;
      int i = tri - ip * (ip - 1) / 2;
      int d = dd >> 3, dp = dd & 7;
      const float* a = WinN + (size_t)(ip * 8 + d) * 512;
      float s = 0.f;
      for (int c = lane; c < 512; c += 64) s += a[c] * WoutS[(size_t)c * 80 + i * 8 + dp];
      #pragma unroll
      for (int o = 32; o; o >>= 1) s += __shfl_xor(s, o);
      if (lane == 0) ws[OFF_PT + (size_t)tri * 65 + dd] = s;
    } else if (gw < 2376) {
      int r = gw - 2304;
      int i = r >> 3;
      const float* a = WinN + (size_t)r * 512;
      float s = 0.f;
      for (int c = lane; c < 512; c += 64) {
        float ob = 0.f;
        for (int j = 0; j < i; j++) ob += out_b[j * 512 + c];
        s += a[c] * ob;
      }
      #pragma unroll
      for (int o = 32; o; o >>= 1) s += __shfl_xor(s, o);
      if (lane == 0) ws[OFF_BEFF + r] = in_b[r] - s;
    }
    return;
  }
  const int bid2 = blockIdx.x - 594;
  if (bid2 < 4096) {  // wdsplit
    int idx = bid2 * 256 + tid;
    const float* wd = ws + OFF_WD;
    u16* wdp = (u16*)(ws + OFF_WDP);
    float v = wd[idx];
    unsigned u = __float_as_uint(v);
    wdp[idx] = (u16)(u >> 16);
    float r = v - __uint_as_float(u & 0xFFFF0000u);
    unsigned ur = __float_as_uint(r);
    wdp[APS + idx] = (u16)(ur >> 16);
    float r2 = r - __uint_as_float(ur & 0xFFFF0000u);
    wdp[2 * APS + idx] = (u16)(__float_as_uint(r2) >> 16);
    return;
  }
  // prep_wx
  __shared__ float Wes[16][512];
  __shared__ float WSs[64][80];
  const float* weff = ws + OFF_WEFF;
  const float* wouts = ws + OFF_WOUTS;
  float* wx = ws + OFF_WX;
  const int m0 = (bid2 - 4096) * 16;
  #pragma unroll
  for (int rep = 0; rep < 32; rep++) {
    int f = tid + rep * 256;
    Wes[f >> 9][f & 511] = weff[(size_t)(m0 + (f >> 9)) * 512 + (f & 511)];
  }
  const int rowq = tid >> 4, rq = tid & 15;
  float accs[5] = {0.f, 0.f, 0.f, 0.f, 0.f};
  for (int k0 = 0; k0 < 512; k0 += 64) {
    __syncthreads();
    #pragma unroll
    for (int rep = 0; rep < 20; rep++) {
      int f = tid + rep * 256;
      int kk = f / 80, col = f % 80;
      WSs[kk][col] = wouts[(size_t)(k0 + kk) * 80 + col];
    }
    __syncthreads();
    #pragma unroll 4
    for (int kk = 0; kk < 64; kk++) {
      float we = Wes[rowq][k0 + kk];
      #pragma unroll
      for (int s = 0; s < 5; s++) accs[s] = fmaf(we, WSs[kk][rq + 16 * s], accs[s]);
    }
  }
  #pragma unroll
  for (int s = 0; s < 5; s++) {
    int r = rq + 16 * s;
    if (r < 73) wx[(size_t)(m0 + rowq) * 80 + r] = accs[s];
  }
  if (tid < 112) {
    int row = tid / 7, col = 73 + tid % 7;
    wx[(size_t)(m0 + row) * 80 + col] = 0.f;
  }
}

// ---------------- gemm_down (R17 verbatim: 128x128, 4 waves, 277us) ----------------
__global__ __launch_bounds__(256) void gemm_down(const u16* __restrict__ Ap,
                                                 const float* __restrict__ z,
                                                 const float* __restrict__ bias,
                                                 float* __restrict__ Out) {
  constexpr int NS = 3, K = 2048;
  __shared__ u16 Bp[2][NS][128][32];
  const int tid = threadIdx.x;
  const int w = tid >> 6, l = tid & 63;
  const int g = l >> 4, li = l & 15;
  const int wr = w >> 1, wc = w & 1;
  const int n0 = blockIdx.x * 128, m0 = blockIdx.y * 128;
  const int nn = tid & 127, kw = tid >> 7;
  const int bb = n0 >> 11;
  const int tb = (n0 & 2047) + nn;

  f32x4 acc[4][4];
  #pragma unroll
  for (int a = 0; a < 4; a++)
    #pragma unroll
    for (int b = 0; b < 4; b++) acc[a][b] = (f32x4){0.f, 0.f, 0.f, 0.f};

  float pvA[16], pvB[16];

#define LOADB(PV, K0)                                                           \
  {                                                                             \
    int c0_ = ((K0) >> 2) + kw * 4;                                             \
    _Pragma("unroll")                                                           \
    for (int cc_ = 0; cc_ < 4; ++cc_)                                           \
      *(float4*)&PV[4 * cc_] =                                                  \
          *(const float4*)(z + ((size_t)(bb * 512 + c0_ + cc_) << 13) + 4 * tb);\
  }

  const int sw = (nn >> 1) & 3;
  const int c0 = ((2 * kw) ^ sw) << 3, c1 = ((2 * kw + 1) ^ sw) << 3;

#define STAGE(BUF, PV)                                                          \
  {                                                                             \
    su16x8 pa_[NS], pb_[NS];                                                    \
    _Pragma("unroll")                                                           \
    for (int j_ = 0; j_ < 8; ++j_) {                                            \
      {                                                                         \
        float v_ = PV[j_];                                                      \
        unsigned u_ = __float_as_uint(v_);                                      \
        pa_[0][j_] = (u16)(u_ >> 16);                                           \
        float r_ = v_ - __uint_as_float(u_ & 0xFFFF0000u);                      \
        unsigned ur_ = __float_as_uint(r_);                                     \
        pa_[1][j_] = (u16)(ur_ >> 16);                                          \
        float r2_ = r_ - __uint_as_float(ur_ & 0xFFFF0000u);                    \
        pa_[2][j_] = (u16)(__float_as_uint(r2_) >> 16);                         \
      }                                                                         \
      {                                                                         \
        float v_ = PV[8 + j_];                                                  \
        unsigned u_ = __float_as_uint(v_);                                      \
        pb_[0][j_] = (u16)(u_ >> 16);                                           \
        float r_ = v_ - __uint_as_float(u_ & 0xFFFF0000u);                      \
        unsigned ur_ = __float_as_uint(r_);                                     \
        pb_[1][j_] = (u16)(ur_ >> 16);                                          \
        float r2_ = r_ - __uint_as_float(ur_ & 0xFFFF0000u);                    \
        pb_[2][j_] = (u16)(__float_as_uint(r2_) >> 16);                         \
      }                                                                         \
    }                                                                           \
    _Pragma("unroll")                                                           \
    for (int p_ = 0; p_ < NS; ++p_) {                                           \
      *(su16x8*)&Bp[BUF][p_][nn][c0] = pa_[p_];                                 \
      *(su16x8*)&Bp[BUF][p_][nn][c1] = pb_[p_];                                 \
    }                                                                           \
  }

#define COMPUTE(BUF, K0)                                                        \
  {                                                                             \
    bf16x8 bfr_[4][NS];                                                         \
    _Pragma("unroll")                                                           \
    for (int fn_ = 0; fn_ < 4; ++fn_) {                                         \
      int row_ = wc * 64 + fn_ * 16 + li;                                       \
      int cs_ = ((g ^ ((row_ >> 1) & 3)) << 3);                                 \
      _Pragma("unroll")                                                         \
      for (int q_ = 0; q_ < NS; ++q_)                                           \
        bfr_[fn_][q_] = *(const bf16x8*)&Bp[BUF][q_][row_][cs_];                \
    }                                                                           \
    const u16* arow_ = Ap + (size_t)(m0 + wr * 64 + li) * K + (K0) + g * 8;     \
    _Pragma("unroll")                                                           \
    for (int fm_ = 0; fm_ < 4; ++fm_) {                                         \
      bf16x8 afr_[NS];                                                          \
      _Pragma("unroll")                                                         \
      for (int p_ = 0; p_ < NS; ++p_)                                           \
        afr_[p_] = *(const bf16x8*)(arow_ + (size_t)p_ * APS + (size_t)fm_ * 16 * K); \
      _Pragma("unroll")                                                         \
      for (int fn_ = 0; fn_ < 4; ++fn_) {                                       \
        f32x4 a_ = acc[fm_][fn_];                                               \
        a_ = __builtin_amdgcn_mfma_f32_16x16x32_bf16(afr_[2], bfr_[fn_][0], a_, 0, 0, 0); \
        a_ = __builtin_amdgcn_mfma_f32_16x16x32_bf16(afr_[1], bfr_[fn_][1], a_, 0, 0, 0); \
        a_ = __builtin_amdgcn_mfma_f32_16x16x32_bf16(afr_[0], bfr_[fn_][2], a_, 0, 0, 0); \
        a_ = __builtin_amdgcn_mfma_f32_16x16x32_bf16(afr_[1], bfr_[fn_][0], a_, 0, 0, 0); \
        a_ = __builtin_amdgcn_mfma_f32_16x16x32_bf16(afr_[0], bfr_[fn_][1], a_, 0, 0, 0); \
        a_ = __builtin_amdgcn_mfma_f32_16x16x32_bf16(afr_[0], bfr_[fn_][0], a_, 0, 0, 0); \
        acc[fm_][fn_] = a_;                                                     \
      }                                                                         \
    }                                                                           \
  }

  LOADB(pvA, 0)
  LOADB(pvB, 32)
  STAGE(0, pvA)
  LOADB(pvA, 64)
  __syncthreads();

  for (int k0 = 0; k0 < K; k0 += 64) {
    STAGE(1, pvB)
    if (k0 + 96 < K) { LOADB(pvB, k0 + 96) }
    COMPUTE(0, k0)
    __syncthreads();
    if (k0 + 64 < K) { STAGE(0, pvA) }
    if (k0 + 128 < K) { LOADB(pvA, k0 + 128) }
    COMPUTE(1, k0 + 32)
    __syncthreads();
  }
#undef LOADB
#undef STAGE
#undef COMPUTE

  const int mb = m0 + wr * 64 + g * 4;
  const int nb = n0 + wc * 64 + li;
  #pragma unroll
  for (int fn = 0; fn < 4; ++fn) {
    int n = nb + fn * 16;
    int b = n >> 11, t = n & 2047;
    #pragma unroll
    for (int fm = 0; fm < 4; ++fm)
      #pragma unroll
      for (int r = 0; r < 4; ++r) {
        int o = mb + fm * 16 + r;
        Out[((size_t)((b << 9) + o)) * 2048 + t] = acc[fm][fn][r] + bias[o];
      }
  }
}

// ---------------- gemm_e0f (R14 verbatim): e0t = WinN @ x2, BN=64 ----------------
__global__ __launch_bounds__(256) void gemm_e0f(const float* __restrict__ A,
                                                const float* __restrict__ Bsrc,
                                                float* __restrict__ e0t) {
  constexpr int M = 72, K = 512, Tt = 2048;
  __shared__ float As[16][132];
  __shared__ float Bs[16][68];
  int tid = threadIdx.x;
  int tx = tid & 7, ty = tid >> 3;
  int n0 = blockIdx.x * 64;
  int b = n0 / Tt, t0 = n0 % Tt;
  float acc[4][8];
  #pragma unroll
  for (int i = 0; i < 4; i++)
    #pragma unroll
    for (int j = 0; j < 8; j++) acc[i][j] = 0.f;

  for (int k0 = 0; k0 < K; k0 += 16) {
    #pragma unroll
    for (int rep = 0; rep < 2; rep++) {
      int f = tid + rep * 256;
      int row = f >> 2, c4 = (f & 3) << 2;
      int m = row, k = k0 + c4;
      float4 v = make_float4(0.f, 0.f, 0.f, 0.f);
      if (m < M) v = *(const float4*)(A + (size_t)m * K + k);
      As[c4 + 0][row] = v.x; As[c4 + 1][row] = v.y;
      As[c4 + 2][row] = v.z; As[c4 + 3][row] = v.w;
    }
    {
      int kk = tid >> 4, n4 = (tid & 15) << 2;
      float4 v = *(const float4*)(Bsrc + ((size_t)(b * K + k0 + kk)) * Tt + t0 + n4);
      *(float4*)&Bs[kk][n4] = v;
    }
    __syncthreads();
    #pragma unroll
    for (int kk = 0; kk < 16; kk++) {
      float a[4], bb[8];
      #pragma unroll
      for (int i = 0; i < 4; i++) a[i] = As[kk][ty * 4 + i];
      *(float4*)&bb[0] = *(float4*)&Bs[kk][tx * 8];
      *(float4*)&bb[4] = *(float4*)&Bs[kk][tx * 8 + 4];
      #pragma unroll
      for (int i = 0; i < 4; i++)
        #pragma unroll
        for (int j = 0; j < 8; j++) acc[i][j] = fmaf(a[i], bb[j], acc[i][j]);
    }
    __syncthreads();
  }
  #pragma unroll
  for (int j = 0; j < 8; j++) {
    int n = n0 + tx * 8 + j;
    #pragma unroll
    for (int i = 0; i < 4; i++) {
      int m = ty * 4 + i;
      if (m < M) e0t[(size_t)n * M + m] = acc[i][j];
    }
  }
}

// ---------------- RVQ core: 32 tokens/block, 512 thr (per-token chains locked) ----------------
__global__ __launch_bounds__(512) void rvq_kernel(const float* __restrict__ codebooks,
                                                  const float* __restrict__ e0t,
                                                  const float* __restrict__ cbsW,
                                                  const float* __restrict__ ptW,
                                                  const float* __restrict__ beffW,
                                                  float* __restrict__ Qout,
                                                  float* __restrict__ codesOut,
                                                  float* __restrict__ lossPart) {
  __shared__ float cbv[8][1024];
  __shared__ float cbs2[2][1024];
  __shared__ float est[32][72];
  __shared__ float lred[8];
  int tid = threadIdx.x, wid = tid >> 6, lane = tid & 63;
  int nb0 = blockIdx.x * 32;
  for (int idx = tid; idx < 32 * 72; idx += 512)
    est[idx / 72][idx % 72] = e0t[(size_t)nb0 * 72 + idx] + beffW[idx % 72];
  float lossLocal = 0.f;

  for (int i = 0; i < NQ; i++) {
    __syncthreads();
    const float* cbg = codebooks + (size_t)i * CBS * CBD;
    for (int lin = tid; lin < 2048; lin += 512) {
      int j = lin >> 1, half = (lin & 1) << 2;
      float4 v = *(const float4*)(cbg + (size_t)j * 8 + half);
      cbv[half + 0][j] = v.x; cbv[half + 1][j] = v.y;
      cbv[half + 2][j] = v.z; cbv[half + 3][j] = v.w;
    }
    for (int lin = tid; lin < 1024; lin += 512) {
      cbs2[0][lin] = cbsW[((size_t)i * 2 + 0) * 1024 + lin];
      cbs2[1][lin] = cbsW[((size_t)i * 2 + 1) * 1024 + lin];
    }
    __syncthreads();

    float ze[4][8], en[4][8];
    #pragma unroll
    for (int w = 0; w < 4; w++) {
      int tokl = wid * 4 + w;
      float ss = 0.f;
      #pragma unroll
      for (int d = 0; d < 8; d++) { float v = est[tokl][i * 8 + d]; ze[w][d] = v; ss += v * v; }
      float inv = 1.0f / fmaxf(sqrtf(ss), EPSN);
      #pragma unroll
      for (int d = 0; d < 8; d++) en[w][d] = ze[w][d] * inv;
    }
    float best[4]; int bidx[4];
    #pragma unroll
    for (int w = 0; w < 4; w++) { best[w] = -INFINITY; bidx[w] = 0; }
    #pragma unroll 4
    for (int r = 0; r < 16; r++) {
      int j = lane + (r << 6);
      float c0 = cbv[0][j], c1 = cbv[1][j], c2 = cbv[2][j], c3 = cbv[3][j];
      float c4 = cbv[4][j], c5 = cbv[5][j], c6 = cbv[6][j], c7 = cbv[7][j];
      float ti = cbs2[0][j], ns = cbs2[1][j];
      #pragma unroll
      for (int w = 0; w < 4; w++) {
        float dt = en[w][0] * c0;
        dt = fmaf(en[w][1], c1, dt); dt = fmaf(en[w][2], c2, dt);
        dt = fmaf(en[w][3], c3, dt); dt = fmaf(en[w][4], c4, dt);
        dt = fmaf(en[w][5], c5, dt); dt = fmaf(en[w][6], c6, dt);
        dt = fmaf(en[w][7], c7, dt);
        float s = fmaf(dt, ti, -ns);
        if (s > best[w]) { best[w] = s; bidx[w] = j; }
      }
    }
    #pragma unroll
    for (int w = 0; w < 4; w++) {
      #pragma unroll
      for (int off = 32; off; off >>= 1) {
        float so = __shfl_xor(best[w], off);
        int jo = __shfl_xor(bidx[w], off);
        if (so > best[w] || (so == best[w] && jo < bidx[w])) { best[w] = so; bidx[w] = jo; }
      }
    }
    int d = lane & 7;
    #pragma unroll
    for (int w = 0; w < 4; w++) {
      int jstar = bidx[w];
      int tokl = wid * 4 + w;
      int n = nb0 + tokl;
      float qd = cbv[d][jstar];
      float diff = ze[w][d] - qd;
      float sq = diff * diff;
      sq += __shfl_xor(sq, 1); sq += __shfl_xor(sq, 2); sq += __shfl_xor(sq, 4);
      if (lane == 0) lossLocal += sq;
      if (lane < 8) Qout[(size_t)n * 80 + i * 8 + lane] = qd;
      if (lane == 0) codesOut[(size_t)((n >> 11) * NQ + i) * TQ + (n & (TQ - 1))] = (float)jstar;
      if (i < NQ - 1) {
        int f = lane >> 3, d2 = lane & 7;
        int ip = i + 1 + f;
        if (ip < NQ) {
          int tri = (ip * (ip - 1)) / 2 + i;
          const float* prow = ptW + (size_t)tri * 65 + d2 * 8;
          float s = 0.f;
          #pragma unroll
          for (int dp = 0; dp < 8; dp++) s = fmaf(prow[dp], cbv[dp][jstar], s);
          est[tokl][ip * 8 + d2] -= s;
        }
      }
    }
  }
  if (lane == 0) lred[wid] = lossLocal;
  __syncthreads();
  if (tid == 0) {
    float s = lred[0];
    #pragma unroll
    for (int q = 1; q < 8; q++) s += lred[q];
    lossPart[blockIdx.x] = s;
  }
}

// ---------------- xfin + loss_fin merged (grid dim3(129,16)) ----------------
__global__ __launch_bounds__(256) void xfin_loss(const float* __restrict__ wx,
                                                 const float* __restrict__ Q,
                                                 const float* __restrict__ bup,
                                                 const float* __restrict__ lossPart,
                                                 float* __restrict__ xout,
                                                 float* __restrict__ lossOut) {
  const int tid = threadIdx.x;
  if (blockIdx.x == 128) {
    if (blockIdx.y != 0) return;
    __shared__ float s[256];
    float v = lossPart[tid] + lossPart[tid + 256];
    s[tid] = v;
    __syncthreads();
    for (int w = 128; w; w >>= 1) {
      if (tid < w) s[tid] += s[tid + w];
      __syncthreads();
    }
    if (tid == 0) {
      float total = s[0] / 131072.0f;
      lossOut[0] = total;
      lossOut[1] = total;
    }
    return;
  }
  __shared__ float Wxs[128][80];
  __shared__ float Qs[128][80];
  const int n0 = blockIdx.x * 128, m0 = blockIdx.y * 128;
  #pragma unroll
  for (int rep = 0; rep < 10; rep++) {
    int f = tid + rep * 256;
    *(float4*)&Wxs[0][f * 4] = *(const float4*)(wx + (size_t)m0 * 80 + f * 4);
    *(float4*)&Qs[0][f * 4] = *(const float4*)(Q + (size_t)n0 * 80 + f * 4);
  }
  __syncthreads();

  const int txn = tid & 15, tym = tid >> 4;
  float acc[8][8];
  #pragma unroll
  for (int i = 0; i < 8; i++)
    #pragma unroll
    for (int j = 0; j < 8; j++) acc[i][j] = 0.f;

  #pragma unroll 2
  for (int r4 = 0; r4 < 18; r4++) {
    float4 wv[8], qv[8];
    #pragma unroll
    for (int i = 0; i < 8; i++) wv[i] = *(const float4*)&Wxs[tym * 8 + i][r4 * 4];
    #pragma unroll
    for (int j = 0; j < 8; j++) qv[j] = *(const float4*)&Qs[txn * 8 + j][r4 * 4];
    #pragma unroll
    for (int i = 0; i < 8; i++)
      #pragma unroll
      for (int j = 0; j < 8; j++) {
        acc[i][j] = fmaf(wv[i].x, qv[j].x, acc[i][j]);
        acc[i][j] = fmaf(wv[i].y, qv[j].y, acc[i][j]);
        acc[i][j] = fmaf(wv[i].z, qv[j].z, acc[i][j]);
        acc[i][j] = fmaf(wv[i].w, qv[j].w, acc[i][j]);
      }
  }

  float bxv[8];
  #pragma unroll
  for (int mi = 0; mi < 8; mi++) {
    int mp = m0 + tym * 8 + mi;
    bxv[mi] = Wxs[tym * 8 + mi][72] + bup[(mp >> 2) * 2 + (mp & 1)];
  }
  #pragma unroll
  for (int cg = 0; cg < 2; cg++) {
    int mp0 = m0 + tym * 8 + cg * 4;
    int c = mp0 >> 2;
    #pragma unroll
    for (int j = 0; j < 8; j++) {
      int n = n0 + txn * 8 + j;
      int b = n >> 11, t = n & 2047;
      float4 sv = make_float4(acc[cg * 4 + 0][j] + bxv[cg * 4 + 0],
                              acc[cg * 4 + 1][j] + bxv[cg * 4 + 1],
                              acc[cg * 4 + 2][j] + bxv[cg * 4 + 2],
                              acc[cg * 4 + 3][j] + bxv[cg * 4 + 3]);
      *(float4*)&xout[((size_t)((b << 9) + c)) * 8192 + 4 * t] = sv;
    }
  }
}

// ---------------- launch ----------------
extern "C" void kernel_launch(void* const* d_in, const int* in_sizes, int n_in,
                              void* d_out, int out_size, void* d_ws, size_t ws_size,
                              hipStream_t stream) {
  const float* z      = (const float*)d_in[0];
  const float* down_w = (const float*)d_in[1];
  const float* down_b = (const float*)d_in[2];
  const float* up_w   = (const float*)d_in[3];
  const float* up_b   = (const float*)d_in[4];
  const float* in_v   = (const float*)d_in[5];
  const float* in_g   = (const float*)d_in[6];
  const float* in_b   = (const float*)d_in[7];
  const float* out_v  = (const float*)d_in[8];
  const float* out_g  = (const float*)d_in[9];
  const float* out_b  = (const float*)d_in[10];
  const float* codebooks = (const float*)d_in[11];
  float* ws = (float*)d_ws;
  float* xout = (float*)d_out;
  float* codesOut = xout + (size_t)8 * 512 * 8192;
  float* lossOut = codesOut + (size_t)8 * NQ * TQ;

  hipLaunchKernelGGL(prep_all1, dim3(718), dim3(256), 0, stream,
                     in_v, in_g, out_v, out_g, out_b, codebooks,
                     down_w, down_b, up_w, up_b, ws);
  hipLaunchKernelGGL(prep_all2, dim3(4818), dim3(256), 0, stream, in_b, out_b, ws);
  // fused down: x2 = W_d(3-split) @ zg + b_d
  hipLaunchKernelGGL(gemm_down, dim3(128, 4), dim3(256), 0, stream,
                     (const u16*)(ws + OFF_WDP), z, ws + OFF_BD, ws + OFF_X2);
  // e0t = WinN @ x2 (full-chip)
  hipLaunchKernelGGL(gemm_e0f, dim3(256), dim3(256), 0, stream,
                     ws + OFF_WINN, ws + OFF_X2, ws + OFF_E0T);
  // RVQ (32 tokens/block)
  hipLaunchKernelGGL(rvq_kernel, dim3(512), dim3(512), 0, stream,
                     codebooks, ws + OFF_E0T, ws + OFF_CBS, ws + OFF_PT, ws + OFF_BEFF,
                     ws + OFF_Q, codesOut, ws + OFF_LOSS);
  // x = Wx @ Q + bx  (+ loss finalize)
  hipLaunchKernelGGL(xfin_loss, dim3(129, 16), dim3(256), 0, stream,
                     ws + OFF_WX, ws + OFF_Q, ws + OFF_BUP, ws + OFF_LOSS,
                     xout, lossOut);
}